// Round 11
// baseline (1374.651 us; speedup 1.0000x reference)
//
#include <hip/hip_runtime.h>
#include <stdint.h>

#define NPTS 131072

// ---------- helpers (XLA:GPU contraction semantics: fma-fused) ----------

__device__ __forceinline__ float cubw(float t) {
#pragma clang fp contract(off)
  float at = fabsf(t);
  if (at <= 1.0f) {
    // ((a+2)*at - (a+3))*at*at + 1  ->  fma(1.25,at,-2.25)*at, fma(.,at,1)
    float u = fmaf(1.25f, at, -2.25f);
    u = u * at;
    return fmaf(u, at, 1.0f);
  } else if (at < 2.0f) {
    // (((at-5)*at + 8)*at - 4)*a
    float u = at - 5.0f;
    u = fmaf(u, at, 8.0f);
    u = fmaf(u, at, -4.0f);
    return u * -0.75f;
  }
  return 0.0f;
}

// quants[t] = (t+1)/64 exactly (XLA linspace: start + iota*delta, delta=1/64 exact)
__device__ __forceinline__ float quant_frac(int t) {
#pragma clang fp contract(off)
  return (float)(t + 1) * 0.015625f;
}

// grid[i] = i * fl32(1/63) (XLA linspace: 0 + iota*delta)
__device__ __forceinline__ float grid_val(int i) {
#pragma clang fp contract(off)
  return (float)i * (1.0f / 63.0f);
}

// XLA:GPU quantile lerp: fma(vlo, lw, fl(vhi*hw)); q exact, never integer.
__device__ __forceinline__ float jax_quantile_lerp(float vlo, float vhi, float q) {
#pragma clang fp contract(off)
  float lowf = floorf(q);
  float highf = ceilf(q);
  float hw = q - lowf;
  float lw = highf - q;
  float bh = vhi * hw;
  return fmaf(vlo, lw, bh);
}

// XLA:GPU bilinear combine: fma(a, 1-w, fl(b*w))
__device__ __forceinline__ float bilerp1(float a, float b, float w) {
#pragma clang fp contract(off)
  float omw = 1.0f - w;
  float bw = b * w;
  return fmaf(a, omw, bw);
}

// ---------- key building ----------

__global__ __launch_bounds__(256) void k_keys1(const float* __restrict__ coords,
                                               uint32_t* __restrict__ ka) {
#pragma clang fp contract(off)
  int i = blockIdx.x * 256 + threadIdx.x;
  int b = i >> 17, idx = i & (NPTS - 1);
  float c = coords[(size_t)(b * 2) * NPTS + idx] + (float)(8 * b);
  ka[i] = __float_as_uint(c);
}

__global__ __launch_bounds__(256) void k_bkey1(const float* __restrict__ coords,
                                               const float* __restrict__ qb1,
                                               uint32_t* __restrict__ ka) {
#pragma clang fp contract(off)
  __shared__ float qb[63];
  int i = blockIdx.x * 256 + threadIdx.x;
  int b = i >> 17, idx = i & (NPTS - 1);
  if (threadIdx.x < 63) qb[threadIdx.x] = qb1[b * 64 + threadIdx.x];
  __syncthreads();
  float c = coords[(size_t)(b * 2) * NPTS + idx] + (float)(8 * b);
  uint32_t d = 0;
#pragma unroll
  for (int k = 0; k < 63; ++k) d += (qb[k] <= c) ? 1u : 0u;
  ka[i] = (d << 17) | (uint32_t)idx;
}

// ---------- hybrid bitonic sort: 8 segments of 131072 ----------

__global__ __launch_bounds__(256) void k_bsort_local(uint32_t* __restrict__ buf) {
  __shared__ uint32_t s[2048];
  const int tid = threadIdx.x;
  const int chunk = blockIdx.x;
  uint32_t* p = buf + (size_t)chunk * 2048;
  const bool desc = (chunk & 1);
  for (int i = tid; i < 2048; i += 256) s[i] = p[i];
  __syncthreads();
  for (int k = 2; k <= 2048; k <<= 1) {
    for (int j = k >> 1; j > 0; j >>= 1) {
      for (int i = tid; i < 2048; i += 256) {
        int ixj = i ^ j;
        if (ixj > i) {
          uint32_t a = s[i], c2 = s[ixj];
          bool up = (((i & k) == 0) != desc);
          if ((a > c2) == up) { s[i] = c2; s[ixj] = a; }
        }
      }
      __syncthreads();
    }
  }
  for (int i = tid; i < 2048; i += 256) p[i] = s[i];
}

__global__ __launch_bounds__(256) void k_bsort_global(uint32_t* __restrict__ buf,
                                                      int k, int j) {
  int gid = blockIdx.x * 256 + threadIdx.x;
  int i = gid & (NPTS - 1);
  int batch = gid >> 17;
  int ixj = i ^ j;
  if (ixj <= i) return;
  uint32_t* p = buf + (size_t)batch * NPTS;
  uint32_t a = p[i], c2 = p[ixj];
  bool up = ((i & k) == 0);
  if ((a > c2) == up) { p[i] = c2; p[ixj] = a; }
}

__global__ __launch_bounds__(256) void k_bsort_localfin(uint32_t* __restrict__ buf,
                                                        int k) {
  __shared__ uint32_t s[2048];
  const int tid = threadIdx.x;
  const int chunk = blockIdx.x;
  const int t = chunk & 63;
  const bool up = ((((unsigned)t << 11) & (unsigned)k) == 0);
  uint32_t* p = buf + (size_t)chunk * 2048;
  for (int i = tid; i < 2048; i += 256) s[i] = p[i];
  __syncthreads();
  for (int j = 1024; j > 0; j >>= 1) {
    for (int i = tid; i < 2048; i += 256) {
      int ixj = i ^ j;
      if (ixj > i) {
        uint32_t a = s[i], c2 = s[ixj];
        if ((a > c2) == up) { s[i] = c2; s[ixj] = a; }
      }
    }
    __syncthreads();
  }
  for (int i = tid; i < 2048; i += 256) p[i] = s[i];
}

// ---------- level-1 quantiles ----------

__global__ __launch_bounds__(64) void k_quantile1(const uint32_t* __restrict__ sorted,
                                                  float* __restrict__ qb1) {
#pragma clang fp contract(off)
  int batch = blockIdx.x, t = threadIdx.x;
  if (t >= 63) return;
  float qv = quant_frac(t);
  float q = qv * 131071.0f;  // exact ((t+1)*131071 < 2^23)
  int lo = (int)floorf(q);
  const uint32_t* s = sorted + (size_t)batch * NPTS;
  qb1[batch * 64 + t] =
      jax_quantile_lerp(__uint_as_float(s[lo]), __uint_as_float(s[lo + 1]), q);
}

// ---------- level-2 ----------

#define BITONIC2048(arr)                                      \
  for (int k = 2; k <= 2048; k <<= 1) {                       \
    for (int j = k >> 1; j > 0; j >>= 1) {                    \
      for (int i = tid; i < 2048; i += 256) {                 \
        int ixj = i ^ j;                                      \
        if (ixj > i) {                                        \
          uint32_t a = arr[i], c2 = arr[ixj];                 \
          bool up = ((i & k) == 0);                           \
          if ((a > c2) == up) { arr[i] = c2; arr[ixj] = a; }  \
        }                                                     \
      }                                                       \
      __syncthreads();                                        \
    }                                                         \
  }

__global__ __launch_bounds__(256) void k_level2(const uint32_t* __restrict__ ka,
                                                const float* __restrict__ coords,
                                                int* __restrict__ idxT,
                                                float* __restrict__ cm) {
#pragma clang fp contract(off)
  __shared__ int gidx[2048];
  __shared__ float ckey[2048];
  __shared__ uint32_t sb[2048];
  __shared__ float qb[63];

  const int tid = threadIdx.x;
  const int row = blockIdx.x;
  const int b = row >> 6, i1 = row & 63;
  const float offf = (float)(512 * row);

  for (int j = tid; j < 2048; j += 256) {
    int g = (int)(ka[(size_t)b * NPTS + i1 * 2048 + j] & 0x1FFFFu);
    gidx[j] = g;
    float cv = coords[((size_t)(b * 2 + 1)) * NPTS + g] + offf;
    ckey[j] = cv;
    sb[j] = __float_as_uint(cv);
  }
  __syncthreads();

  BITONIC2048(sb)

  if (tid < 63) {
    float qv = quant_frac(tid);
    float q = qv * 2047.0f;  // exact
    int lo = (int)floorf(q);
    qb[tid] = jax_quantile_lerp(__uint_as_float(sb[lo]), __uint_as_float(sb[lo + 1]), q);
  }
  __syncthreads();

  for (int j = tid; j < 2048; j += 256) {
    float cv = ckey[j];
    uint32_t d = 0;
#pragma unroll
    for (int k = 0; k < 63; ++k) d += (qb[k] <= cv) ? 1u : 0u;
    sb[j] = (d << 11) | (uint32_t)j;
  }
  __syncthreads();

  BITONIC2048(sb)

  for (int p = tid; p < 2048; p += 256)
    idxT[(size_t)b * NPTS + i1 * 2048 + p] = gidx[sb[p] & 0x7FFu];

  if (tid < 128) {
    int i2 = tid >> 1, d = tid & 1;
    float v[32];
#pragma unroll
    for (int m2 = 0; m2 < 32; ++m2)
      v[m2] = coords[((size_t)(b * 2 + d)) * NPTS + gidx[sb[i2 * 32 + m2] & 0x7FFu]];
#pragma unroll
    for (int r = 0; r < 32; ++r) {
#pragma unroll
      for (int i = (r & 1); i + 1 < 32; i += 2) {
        float a = v[i], c2 = v[i + 1];
        v[i] = fminf(a, c2);
        v[i + 1] = fmaxf(a, c2);
      }
    }
    cm[(((size_t)(b * 2 + d)) * 64 + i1) * 64 + i2] = v[15];
  }
}

// ---------- pad + two-pass bilinear (fma) + argmin0, fused per batch ----------

__global__ __launch_bounds__(256) void k_coordsel(const float* __restrict__ cm,
                                                  int* __restrict__ ind0t,
                                                  float* __restrict__ c1sel) {
#pragma clang fp contract(off)
  __shared__ float cp0[66][66];
  __shared__ float cp1[66][66];
  __shared__ int i0v[132];
  __shared__ float wvv[132];
  __shared__ float col0[132], col1[132];

  const int b = blockIdx.x;
  const int tid = threadIdx.x;
  const float* m0 = cm + (size_t)(b * 2) * 4096;
  const float* m1 = cm + (size_t)(b * 2 + 1) * 4096;

  if (tid < 132) {
    const float R = (float)(65.0 / 131.0);
    float pos = (float)tid * R;
    int i0 = (int)floorf(pos);
    if (i0 < 0) i0 = 0;
    if (i0 > 65) i0 = 65;
    i0v[tid] = i0;
    wvv[tid] = pos - (float)i0;
  }

  for (int i = tid; i < 4096; i += 256) {
    int i1 = i >> 6, i2 = i & 63;
    cp0[1 + i1][1 + i2] = m0[i];
    cp1[1 + i1][1 + i2] = m1[i];
  }
  __syncthreads();

  if (tid < 64) {
    int i2 = tid;
    float mn = m0[i2], mx = m0[i2];
    for (int i1 = 1; i1 < 64; ++i1) {
      float v = m0[i1 * 64 + i2];
      mn = fminf(mn, v);
      mx = fmaxf(mx, v);
    }
    cp0[0][1 + i2] = mn - 0.5f;
    cp0[65][1 + i2] = mx + 0.5f;
  } else if (tid < 128) {
    int i1 = tid - 64;
    float mn = m1[i1 * 64], mx = m1[i1 * 64];
    for (int i2 = 1; i2 < 64; ++i2) {
      float v = m1[i1 * 64 + i2];
      mn = fminf(mn, v);
      mx = fmaxf(mx, v);
    }
    cp1[1 + i1][0] = mn - 0.5f;
    cp1[1 + i1][65] = mx + 0.5f;
  }
  __syncthreads();

  if (tid < 66) {
    cp0[tid][0] = cp0[tid][1];
    cp0[tid][65] = cp0[tid][64];
  } else if (tid < 132) {
    int w = tid - 66;
    cp1[0][w] = cp1[1][w];
    cp1[65][w] = cp1[64][w];
  }
  __syncthreads();

  for (int wp = 0; wp < 132; ++wp) {
    int j0 = i0v[wp];
    int j1 = j0 + 1;
    if (j1 > 65) j1 = 65;
    float wu = wvv[wp];
    if (tid < 132) {
      int hp = tid;
      int r0 = i0v[hp];
      int r1 = r0 + 1;
      if (r1 > 65) r1 = 65;
      float wt = wvv[hp];
      // pass 1 (along H) rounded, then pass 2 (along W) -- both fma-contracted
      float t0a = bilerp1(cp0[r0][j0], cp0[r1][j0], wt);
      float t0b = bilerp1(cp0[r0][j1], cp0[r1][j1], wt);
      float t1a = bilerp1(cp1[r0][j0], cp1[r1][j0], wt);
      float t1b = bilerp1(cp1[r0][j1], cp1[r1][j1], wt);
      col0[hp] = bilerp1(t0a, t0b, wu);
      col1[hp] = bilerp1(t1a, t1b, wu);
    }
    __syncthreads();
    if (tid < 64) {
      float gv = grid_val(tid);
      float best = fabsf(col0[0] - gv);
      int bi = 0;
      for (int h = 1; h < 132; ++h) {
        float d2 = fabsf(col0[h] - gv);
        if (d2 < best) { best = d2; bi = h; }
      }
      ind0t[((size_t)b * 64 + tid) * 132 + wp] = bi;
      c1sel[((size_t)b * 64 + tid) * 132 + wp] = col1[bi];
    }
    __syncthreads();
  }
}

__global__ __launch_bounds__(64) void k_sel1b(const float* __restrict__ c1sel,
                                              int* __restrict__ ind) {
#pragma clang fp contract(off)
  __shared__ float rv[132];
  int b = blockIdx.x >> 6, g0 = blockIdx.x & 63;
  int tid = threadIdx.x;
  for (int w = tid; w < 132; w += 64) rv[w] = c1sel[((size_t)b * 64 + g0) * 132 + w];
  __syncthreads();
  float gv = grid_val(tid);
  float best = fabsf(rv[0] - gv);
  int bi = 0;
  for (int w = 1; w < 132; ++w) {
    float d2 = fabsf(rv[w] - gv);
    if (d2 < best) { best = d2; bi = w; }
  }
  ind[((size_t)b * 64 + g0) * 64 + tid] = bi;
}

// ---------- final bicubic (fma accumulation) ----------

__global__ __launch_bounds__(256) void k_final(const float* __restrict__ x,
                                               const int* __restrict__ idxT,
                                               const int* __restrict__ ind,
                                               const int* __restrict__ ind0t,
                                               float* __restrict__ outp) {
#pragma clang fp contract(off)
  int b = blockIdx.x >> 6, p = blockIdx.x & 63;
  int tid = threadIdx.x;
  int qt = tid & 63, cg = tid >> 6;
  const float R = (float)(65.0 / 131.0);

  int wstar = ind[((size_t)b * 64 + qt) * 64 + p];
  int hstar = ind0t[((size_t)b * 64 + qt) * 132 + wstar];

  float posh = (float)hstar * R;
  int i0h = (int)floorf(posh);
  float frh = posh - (float)i0h;
  float posw = (float)wstar * R;
  int i0w = (int)floorf(posw);
  float frw = posw - (float)i0w;

  int ri[4], ci2[4];
  float wh[4], ww[4];
#pragma unroll
  for (int k = 0; k < 4; ++k) {
    int I = i0h + k - 1;
    I = I < 0 ? 0 : (I > 65 ? 65 : I);
    int rI = I - 1;
    ri[k] = rI < 0 ? 0 : (rI > 63 ? 63 : rI);
    wh[k] = cubw(frh - (float)(k - 1));
    int J = i0w + k - 1;
    J = J < 0 ? 0 : (J > 65 ? 65 : J);
    int cJ = J - 1;
    ci2[k] = cJ < 0 ? 0 : (cJ > 63 ? 63 : cJ);
    ww[k] = cubw(frw - (float)(k - 1));
  }

  const int* rT = idxT + (size_t)b * NPTS;
  const float* xb = x + (size_t)b * NPTS * 8;

  for (int m8 = 0; m8 < 8; ++m8) {
    int mi = cg * 8 + m8;
    int G[16];
#pragma unroll
    for (int l = 0; l < 4; ++l)
#pragma unroll
      for (int k = 0; k < 4; ++k)
        G[l * 4 + k] = rT[ri[k] * 2048 + ci2[l] * 32 + mi];
#pragma unroll
    for (int half = 0; half < 2; ++half) {
      int fi = half * 4;
      float ax = 0.0f, ay = 0.0f, az = 0.0f, aw = 0.0f;
#pragma unroll
      for (int l = 0; l < 4; ++l) {
        float tx = 0.0f, ty = 0.0f, tz = 0.0f, tw = 0.0f;
#pragma unroll
        for (int k = 0; k < 4; ++k) {
          const float4 s = *(const float4*)(xb + (size_t)G[l * 4 + k] * 8 + fi);
          tx = fmaf(s.x, wh[k], tx);
          ty = fmaf(s.y, wh[k], ty);
          tz = fmaf(s.z, wh[k], tz);
          tw = fmaf(s.w, wh[k], tw);
        }
        ax = fmaf(tx, ww[l], ax);
        ay = fmaf(ty, ww[l], ay);
        az = fmaf(tz, ww[l], az);
        aw = fmaf(tw, ww[l], aw);
      }
      int ch = mi * 8 + fi;
      size_t o = (((size_t)b * 256 + ch) * 64 + p) * 64 + qt;
      outp[o] = ax;
      outp[o + 4096] = ay;
      outp[o + 8192] = az;
      outp[o + 12288] = aw;
    }
  }
}

// ---------- launch ----------

extern "C" void kernel_launch(void* const* d_in, const int* in_sizes, int n_in,
                              void* d_out, int out_size, void* d_ws, size_t ws_size,
                              hipStream_t stream) {
  (void)n_in; (void)out_size; (void)ws_size;
  const float* x;
  const float* coords;
  if (in_sizes[0] == 8388608) {
    x = (const float*)d_in[0];
    coords = (const float*)d_in[1];
  } else {
    coords = (const float*)d_in[0];
    x = (const float*)d_in[1];
  }
  float* outp = (float*)d_out;
  char* ws = (char*)d_ws;

  uint32_t* KA = (uint32_t*)(ws + 0);        // 4 MB
  float* QB1 = (float*)(ws + 4194304);       // 2 KB
  int* IDXT = (int*)(ws + 4196352);          // 4 MB
  float* CM = (float*)(ws + 8390656);        // 256 KB
  int* IND0T = (int*)(ws + 8652800);         // 264 KB
  float* C1SEL = (float*)(ws + 8923136);     // 264 KB
  int* IND = (int*)(ws + 9193472);           // 128 KB

  auto SORT = [&]() {
    k_bsort_local<<<512, 256, 0, stream>>>(KA);
    for (int k = 4096; k <= 131072; k <<= 1) {
      for (int j = k >> 1; j >= 2048; j >>= 1)
        k_bsort_global<<<4096, 256, 0, stream>>>(KA, k, j);
      k_bsort_localfin<<<512, 256, 0, stream>>>(KA, k);
    }
  };

  k_keys1<<<4096, 256, 0, stream>>>(coords, KA);
  SORT();
  k_quantile1<<<8, 64, 0, stream>>>(KA, QB1);
  k_bkey1<<<4096, 256, 0, stream>>>(coords, QB1, KA);
  SORT();
  k_level2<<<512, 256, 0, stream>>>(KA, coords, IDXT, CM);

  k_coordsel<<<8, 256, 0, stream>>>(CM, IND0T, C1SEL);
  k_sel1b<<<512, 64, 0, stream>>>(C1SEL, IND);
  k_final<<<512, 256, 0, stream>>>(x, IDXT, IND, IND0T, outp);
}

// Round 12
// 778.673 us; speedup vs baseline: 1.7654x; 1.7654x over previous
//
#include <hip/hip_runtime.h>
#include <stdint.h>

#define NPTS 131072

// ---------- helpers (XLA:GPU contraction semantics: fma-fused) ----------

__device__ __forceinline__ float cubw(float t) {
#pragma clang fp contract(off)
  float at = fabsf(t);
  if (at <= 1.0f) {
    float u = fmaf(1.25f, at, -2.25f);
    u = u * at;
    return fmaf(u, at, 1.0f);
  } else if (at < 2.0f) {
    float u = at - 5.0f;
    u = fmaf(u, at, 8.0f);
    u = fmaf(u, at, -4.0f);
    return u * -0.75f;
  }
  return 0.0f;
}

__device__ __forceinline__ float quant_frac(int t) {
#pragma clang fp contract(off)
  return (float)(t + 1) * 0.015625f;
}

__device__ __forceinline__ float grid_val(int i) {
#pragma clang fp contract(off)
  return (float)i * (1.0f / 63.0f);
}

__device__ __forceinline__ float jax_quantile_lerp(float vlo, float vhi, float q) {
#pragma clang fp contract(off)
  float lowf = floorf(q);
  float highf = ceilf(q);
  float hw = q - lowf;
  float lw = highf - q;
  float bh = vhi * hw;
  return fmaf(vlo, lw, bh);
}

__device__ __forceinline__ float bilerp1(float a, float b, float w) {
#pragma clang fp contract(off)
  float omw = 1.0f - w;
  float bw = b * w;
  return fmaf(a, omw, bw);
}

template <int NB>
__device__ __forceinline__ unsigned long long match_mask(uint32_t d) {
  unsigned long long m = ~0ull;
#pragma unroll
  for (int i = 0; i < NB; ++i) {
    unsigned long long bal = __ballot((int)((d >> i) & 1u));
    m &= ((d >> i) & 1u) ? bal : ~bal;
  }
  return m;
}

// ---------- key building ----------

__global__ __launch_bounds__(256) void k_keys1(const float* __restrict__ coords,
                                               uint32_t* __restrict__ ka) {
#pragma clang fp contract(off)
  int i = blockIdx.x * 256 + threadIdx.x;
  int b = i >> 17, idx = i & (NPTS - 1);
  float c = coords[(size_t)(b * 2) * NPTS + idx] + (float)(8 * b);
  ka[i] = __float_as_uint(c);
}

// ---------- LSD radix sort (values only), 8 segments of 131072 ----------

__global__ __launch_bounds__(256) void k_radix_hist(const uint32_t* __restrict__ in,
                                                    uint32_t* __restrict__ hist, int shift) {
  __shared__ uint32_t h[256];
  int tid = threadIdx.x;
  int batch = blockIdx.x >> 5, blk = blockIdx.x & 31;
  h[tid] = 0;
  __syncthreads();
  const uint32_t* keys = in + (size_t)batch * NPTS + (size_t)blk * 4096;
  for (int r = 0; r < 16; ++r) {
    uint32_t d = (keys[r * 256 + tid] >> shift) & 255u;
    atomicAdd(&h[d], 1u);
  }
  __syncthreads();
  hist[((size_t)batch * 256 + tid) * 32 + blk] = h[tid];
}

// per-batch exclusive scan over contiguous [len] (len multiple of 256)
__global__ __launch_bounds__(256) void k_scan(uint32_t* __restrict__ buf, int len) {
  __shared__ uint32_t tot[256];
  int batch = blockIdx.x, tid = threadIdx.x;
  int per = len >> 8;
  uint32_t* p = buf + (size_t)batch * len + (size_t)tid * per;
  uint32_t s = 0;
  for (int i = 0; i < per; ++i) s += p[i];
  tot[tid] = s;
  __syncthreads();
  if (tid == 0) {
    uint32_t run = 0;
    for (int i = 0; i < 256; ++i) { uint32_t t = tot[i]; tot[i] = run; run += t; }
  }
  __syncthreads();
  uint32_t run = tot[tid];
  for (int i = 0; i < per; ++i) { uint32_t t = p[i]; p[i] = run; run += t; }
}

__global__ __launch_bounds__(256) void k_radix_scatter(const uint32_t* __restrict__ in,
                                                       uint32_t* __restrict__ out,
                                                       const uint32_t* __restrict__ base,
                                                       int shift) {
  __shared__ uint32_t whist[4 * 256];
  int tid = threadIdx.x;
  int wv = tid >> 6, lane = tid & 63;
  int batch = blockIdx.x >> 5, blk = blockIdx.x & 31;
  size_t batchbase = (size_t)batch * NPTS;
  const uint32_t* src = in + batchbase + (size_t)blk * 4096 + (size_t)wv * 1024;

  for (int i = tid; i < 4 * 256; i += 256) whist[i] = 0;
  __syncthreads();

  uint32_t keyv[16], posv[16];
#pragma unroll
  for (int r = 0; r < 16; ++r) {
    uint32_t key = src[r * 64 + lane];
    uint32_t d = (key >> shift) & 255u;
    unsigned long long m = match_mask<8>(d);
    unsigned long long below = m & ((1ull << lane) - 1ull);
    uint32_t rank = (uint32_t)__popcll(below);
    uint32_t cnt = (uint32_t)__popcll(m);
    uint32_t bse = whist[wv * 256 + d];
    if (below == 0ull) whist[wv * 256 + d] = bse + cnt;
    keyv[r] = key;
    posv[r] = bse + rank;
  }
  __syncthreads();
  {
    uint32_t a0 = whist[tid], a1 = whist[256 + tid], a2 = whist[512 + tid];
    whist[tid] = 0;
    whist[256 + tid] = a0;
    whist[512 + tid] = a0 + a1;
    whist[768 + tid] = a0 + a1 + a2;
  }
  __syncthreads();
  const uint32_t* bb = base + (size_t)batch * 8192;
#pragma unroll
  for (int r = 0; r < 16; ++r) {
    uint32_t key = keyv[r];
    uint32_t d = (key >> shift) & 255u;
    uint32_t pos = bb[d * 32 + blk] + whist[wv * 256 + d] + posv[r];
    out[batchbase + pos] = key;
  }
}

// ---------- level-1 quantiles ----------

__global__ __launch_bounds__(64) void k_quantile1(const uint32_t* __restrict__ sorted,
                                                  float* __restrict__ qb1) {
#pragma clang fp contract(off)
  int batch = blockIdx.x, t = threadIdx.x;
  if (t >= 63) return;
  float qv = quant_frac(t);
  float q = qv * 131071.0f;
  int lo = (int)floorf(q);
  const uint32_t* s = sorted + (size_t)batch * NPTS;
  qb1[batch * 64 + t] =
      jax_quantile_lerp(__uint_as_float(s[lo]), __uint_as_float(s[lo + 1]), q);
}

// ---------- level-1 stable counting sort by bucket (#{qb <= c}) ----------

__global__ __launch_bounds__(256) void k_bhist(const float* __restrict__ coords,
                                               const float* __restrict__ qb1,
                                               uint32_t* __restrict__ hist) {
#pragma clang fp contract(off)
  __shared__ uint32_t h[64];
  __shared__ float qb[63];
  int tid = threadIdx.x;
  int batch = blockIdx.x >> 5, blk = blockIdx.x & 31;
  if (tid < 64) h[tid] = 0;
  if (tid >= 64 && tid < 127) qb[tid - 64] = qb1[batch * 64 + (tid - 64)];
  __syncthreads();
  const float* c = coords + (size_t)(batch * 2) * NPTS + (size_t)blk * 4096;
  float off = (float)(8 * batch);
  for (int r = 0; r < 16; ++r) {
    float v = c[r * 256 + tid] + off;
    uint32_t d = 0;
#pragma unroll
    for (int k = 0; k < 63; ++k) d += (qb[k] <= v) ? 1u : 0u;
    atomicAdd(&h[d], 1u);
  }
  __syncthreads();
  if (tid < 64) hist[((size_t)batch * 64 + tid) * 32 + blk] = h[tid];
}

__global__ __launch_bounds__(256) void k_bscatter(const float* __restrict__ coords,
                                                  const float* __restrict__ qb1,
                                                  const uint32_t* __restrict__ base,
                                                  int* __restrict__ idxout) {
#pragma clang fp contract(off)
  __shared__ uint32_t whist[4 * 64];
  __shared__ float qb[63];
  int tid = threadIdx.x;
  int wv = tid >> 6, lane = tid & 63;
  int batch = blockIdx.x >> 5, blk = blockIdx.x & 31;
  if (tid < 4 * 64) whist[tid] = 0;
  if (tid >= 192 && tid < 255) qb[tid - 192] = qb1[batch * 64 + (tid - 192)];
  __syncthreads();
  const float* c = coords + (size_t)(batch * 2) * NPTS + (size_t)blk * 4096 + (size_t)wv * 1024;
  float off = (float)(8 * batch);
  uint32_t bkv[16], rkv[16];
#pragma unroll
  for (int r = 0; r < 16; ++r) {
    float v = c[r * 64 + lane] + off;
    uint32_t d = 0;
#pragma unroll
    for (int k = 0; k < 63; ++k) d += (qb[k] <= v) ? 1u : 0u;
    unsigned long long m = match_mask<6>(d);
    unsigned long long below = m & ((1ull << lane) - 1ull);
    uint32_t rank = (uint32_t)__popcll(below);
    uint32_t cnt = (uint32_t)__popcll(m);
    uint32_t bse = whist[wv * 64 + d];
    if (below == 0ull) whist[wv * 64 + d] = bse + cnt;
    bkv[r] = d;
    rkv[r] = bse + rank;
  }
  __syncthreads();
  if (tid < 64) {
    uint32_t a0 = whist[tid], a1 = whist[64 + tid], a2 = whist[128 + tid];
    whist[tid] = 0;
    whist[64 + tid] = a0;
    whist[128 + tid] = a0 + a1;
    whist[192 + tid] = a0 + a1 + a2;
  }
  __syncthreads();
  const uint32_t* bb = base + (size_t)batch * 2048;
  int ibase = blk * 4096 + wv * 1024;
#pragma unroll
  for (int r = 0; r < 16; ++r) {
    uint32_t d = bkv[r];
    uint32_t pos = bb[d * 32 + blk] + whist[wv * 64 + d] + rkv[r];
    idxout[(size_t)batch * NPTS + pos] = ibase + r * 64 + lane;
  }
}

// ---------- level-2 (unchanged arithmetic) ----------

#define BITONIC2048(arr)                                      \
  for (int k = 2; k <= 2048; k <<= 1) {                       \
    for (int j = k >> 1; j > 0; j >>= 1) {                    \
      for (int i = tid; i < 2048; i += 256) {                 \
        int ixj = i ^ j;                                      \
        if (ixj > i) {                                        \
          uint32_t a = arr[i], c2 = arr[ixj];                 \
          bool up = ((i & k) == 0);                           \
          if ((a > c2) == up) { arr[i] = c2; arr[ixj] = a; }  \
        }                                                     \
      }                                                       \
      __syncthreads();                                        \
    }                                                         \
  }

__global__ __launch_bounds__(256) void k_level2(const int* __restrict__ idx1,
                                                const float* __restrict__ coords,
                                                int* __restrict__ idxT,
                                                float* __restrict__ cm) {
#pragma clang fp contract(off)
  __shared__ int gidx[2048];
  __shared__ float ckey[2048];
  __shared__ uint32_t sb[2048];
  __shared__ float qb[63];

  const int tid = threadIdx.x;
  const int row = blockIdx.x;
  const int b = row >> 6, i1 = row & 63;
  const float offf = (float)(512 * row);

  for (int j = tid; j < 2048; j += 256) {
    int g = idx1[(size_t)b * NPTS + i1 * 2048 + j];
    gidx[j] = g;
    float cv = coords[((size_t)(b * 2 + 1)) * NPTS + g] + offf;
    ckey[j] = cv;
    sb[j] = __float_as_uint(cv);
  }
  __syncthreads();

  BITONIC2048(sb)

  if (tid < 63) {
    float qv = quant_frac(tid);
    float q = qv * 2047.0f;
    int lo = (int)floorf(q);
    qb[tid] = jax_quantile_lerp(__uint_as_float(sb[lo]), __uint_as_float(sb[lo + 1]), q);
  }
  __syncthreads();

  for (int j = tid; j < 2048; j += 256) {
    float cv = ckey[j];
    uint32_t d = 0;
#pragma unroll
    for (int k = 0; k < 63; ++k) d += (qb[k] <= cv) ? 1u : 0u;
    sb[j] = (d << 11) | (uint32_t)j;
  }
  __syncthreads();

  BITONIC2048(sb)

  for (int p = tid; p < 2048; p += 256)
    idxT[(size_t)b * NPTS + i1 * 2048 + p] = gidx[sb[p] & 0x7FFu];

  if (tid < 128) {
    int i2 = tid >> 1, d = tid & 1;
    float v[32];
#pragma unroll
    for (int m2 = 0; m2 < 32; ++m2)
      v[m2] = coords[((size_t)(b * 2 + d)) * NPTS + gidx[sb[i2 * 32 + m2] & 0x7FFu]];
#pragma unroll
    for (int r = 0; r < 32; ++r) {
#pragma unroll
      for (int i = (r & 1); i + 1 < 32; i += 2) {
        float a = v[i], c2 = v[i + 1];
        v[i] = fminf(a, c2);
        v[i + 1] = fmaxf(a, c2);
      }
    }
    cm[(((size_t)(b * 2 + d)) * 64 + i1) * 64 + i2] = v[15];
  }
}

// ---------- pad + two-pass bilinear (fma) + argmin0 (unchanged) ----------

__global__ __launch_bounds__(256) void k_coordsel(const float* __restrict__ cm,
                                                  int* __restrict__ ind0t,
                                                  float* __restrict__ c1sel) {
#pragma clang fp contract(off)
  __shared__ float cp0[66][66];
  __shared__ float cp1[66][66];
  __shared__ int i0v[132];
  __shared__ float wvv[132];
  __shared__ float col0[132], col1[132];

  const int b = blockIdx.x;
  const int tid = threadIdx.x;
  const float* m0 = cm + (size_t)(b * 2) * 4096;
  const float* m1 = cm + (size_t)(b * 2 + 1) * 4096;

  if (tid < 132) {
    const float R = (float)(65.0 / 131.0);
    float pos = (float)tid * R;
    int i0 = (int)floorf(pos);
    if (i0 < 0) i0 = 0;
    if (i0 > 65) i0 = 65;
    i0v[tid] = i0;
    wvv[tid] = pos - (float)i0;
  }

  for (int i = tid; i < 4096; i += 256) {
    int i1 = i >> 6, i2 = i & 63;
    cp0[1 + i1][1 + i2] = m0[i];
    cp1[1 + i1][1 + i2] = m1[i];
  }
  __syncthreads();

  if (tid < 64) {
    int i2 = tid;
    float mn = m0[i2], mx = m0[i2];
    for (int i1 = 1; i1 < 64; ++i1) {
      float v = m0[i1 * 64 + i2];
      mn = fminf(mn, v);
      mx = fmaxf(mx, v);
    }
    cp0[0][1 + i2] = mn - 0.5f;
    cp0[65][1 + i2] = mx + 0.5f;
  } else if (tid < 128) {
    int i1 = tid - 64;
    float mn = m1[i1 * 64], mx = m1[i1 * 64];
    for (int i2 = 1; i2 < 64; ++i2) {
      float v = m1[i1 * 64 + i2];
      mn = fminf(mn, v);
      mx = fmaxf(mx, v);
    }
    cp1[1 + i1][0] = mn - 0.5f;
    cp1[1 + i1][65] = mx + 0.5f;
  }
  __syncthreads();

  if (tid < 66) {
    cp0[tid][0] = cp0[tid][1];
    cp0[tid][65] = cp0[tid][64];
  } else if (tid < 132) {
    int w = tid - 66;
    cp1[0][w] = cp1[1][w];
    cp1[65][w] = cp1[64][w];
  }
  __syncthreads();

  for (int wp = 0; wp < 132; ++wp) {
    int j0 = i0v[wp];
    int j1 = j0 + 1;
    if (j1 > 65) j1 = 65;
    float wu = wvv[wp];
    if (tid < 132) {
      int hp = tid;
      int r0 = i0v[hp];
      int r1 = r0 + 1;
      if (r1 > 65) r1 = 65;
      float wt = wvv[hp];
      float t0a = bilerp1(cp0[r0][j0], cp0[r1][j0], wt);
      float t0b = bilerp1(cp0[r0][j1], cp0[r1][j1], wt);
      float t1a = bilerp1(cp1[r0][j0], cp1[r1][j0], wt);
      float t1b = bilerp1(cp1[r0][j1], cp1[r1][j1], wt);
      col0[hp] = bilerp1(t0a, t0b, wu);
      col1[hp] = bilerp1(t1a, t1b, wu);
    }
    __syncthreads();
    if (tid < 64) {
      float gv = grid_val(tid);
      float best = fabsf(col0[0] - gv);
      int bi = 0;
      for (int h = 1; h < 132; ++h) {
        float d2 = fabsf(col0[h] - gv);
        if (d2 < best) { best = d2; bi = h; }
      }
      ind0t[((size_t)b * 64 + tid) * 132 + wp] = bi;
      c1sel[((size_t)b * 64 + tid) * 132 + wp] = col1[bi];
    }
    __syncthreads();
  }
}

__global__ __launch_bounds__(64) void k_sel1b(const float* __restrict__ c1sel,
                                              int* __restrict__ ind) {
#pragma clang fp contract(off)
  __shared__ float rv[132];
  int b = blockIdx.x >> 6, g0 = blockIdx.x & 63;
  int tid = threadIdx.x;
  for (int w = tid; w < 132; w += 64) rv[w] = c1sel[((size_t)b * 64 + g0) * 132 + w];
  __syncthreads();
  float gv = grid_val(tid);
  float best = fabsf(rv[0] - gv);
  int bi = 0;
  for (int w = 1; w < 132; ++w) {
    float d2 = fabsf(rv[w] - gv);
    if (d2 < best) { best = d2; bi = w; }
  }
  ind[((size_t)b * 64 + g0) * 64 + tid] = bi;
}

// ---------- gather x into cell-contiguous DB[b*4096+cell][256] ----------

__global__ __launch_bounds__(256) void k_db(const float* __restrict__ x,
                                            const int* __restrict__ idxT,
                                            float* __restrict__ db) {
  int t = blockIdx.x * 256 + threadIdx.x;  // 1,048,576 = (b,cell,mi)
  int mi = t & 31;
  int cellLocal = (t >> 5) & 4095;
  int b = t >> 17;
  int g = idxT[(size_t)b * NPTS + cellLocal * 32 + mi];
  const float* src = x + ((size_t)b * NPTS + g) * 8;
  float4 lo = *(const float4*)(src);
  float4 hi = *(const float4*)(src + 4);
  float* dst = db + (size_t)t * 8;
  *(float4*)(dst) = lo;
  *(float4*)(dst + 4) = hi;
}

// ---------- final bicubic: lanes=channels (coalesced reads), LDS transpose ----------

__global__ __launch_bounds__(256) void k_final3(const float* __restrict__ db,
                                                const int* __restrict__ ind,
                                                const int* __restrict__ ind0t,
                                                float* __restrict__ outp) {
#pragma clang fp contract(off)
  __shared__ int sRI[256], sCI[256];
  __shared__ float sWH[256], sWW[256];
  __shared__ float tile[64][65];

  const int bid = blockIdx.x;  // b*256 + p*4 + cg
  const int b = bid >> 8;
  const int p = (bid >> 2) & 63;
  const int cg = bid & 3;
  const int tid = threadIdx.x;
  const float R = (float)(65.0 / 131.0);

  if (tid < 64) {
    int qt = tid;
    int wstar = ind[((size_t)b * 64 + qt) * 64 + p];
    int hstar = ind0t[((size_t)b * 64 + qt) * 132 + wstar];
    float posh = (float)hstar * R;
    int i0h = (int)floorf(posh);
    float frh = posh - (float)i0h;
    float posw = (float)wstar * R;
    int i0w = (int)floorf(posw);
    float frw = posw - (float)i0w;
#pragma unroll
    for (int k = 0; k < 4; ++k) {
      int I = i0h + k - 1;
      I = I < 0 ? 0 : (I > 65 ? 65 : I);
      int rI = I - 1;
      sRI[qt * 4 + k] = rI < 0 ? 0 : (rI > 63 ? 63 : rI);
      sWH[qt * 4 + k] = cubw(frh - (float)(k - 1));
      int J = i0w + k - 1;
      J = J < 0 ? 0 : (J > 65 ? 65 : J);
      int cJ = J - 1;
      sCI[qt * 4 + k] = cJ < 0 ? 0 : (cJ > 63 ? 63 : cJ);
      sWW[qt * 4 + k] = cubw(frw - (float)(k - 1));
    }
  }
  __syncthreads();

  const int wave = tid >> 6, lane = tid & 63;
  const int ch = cg * 64 + lane;
  const size_t dbb = (size_t)(b * 4096) * 256 + ch;

  for (int s = 0; s < 16; ++s) {
    int qt = wave * 16 + s;
    float a = 0.0f;
#pragma unroll
    for (int l = 0; l < 4; ++l) {
      float t = 0.0f;
#pragma unroll
      for (int k = 0; k < 4; ++k) {
        float v = db[dbb + (size_t)(sRI[qt * 4 + k] * 64 + sCI[qt * 4 + l]) * 256];
        t = fmaf(v, sWH[qt * 4 + k], t);
      }
      a = fmaf(t, sWW[qt * 4 + l], a);
    }
    tile[qt][lane] = a;
  }
  __syncthreads();

  // write out[b][cg*64+cc][p][qt], coalesced along qt
  for (int it = 0; it < 16; ++it) {
    int qt2 = tid & 63;
    int cc = (tid >> 6) * 16 + it;
    outp[(((size_t)b * 256 + cg * 64 + cc) * 64 + p) * 64 + qt2] = tile[qt2][cc];
  }
}

// ---------- launch ----------

extern "C" void kernel_launch(void* const* d_in, const int* in_sizes, int n_in,
                              void* d_out, int out_size, void* d_ws, size_t ws_size,
                              hipStream_t stream) {
  (void)n_in; (void)out_size; (void)ws_size;
  const float* x;
  const float* coords;
  if (in_sizes[0] == 8388608) {
    x = (const float*)d_in[0];
    coords = (const float*)d_in[1];
  } else {
    coords = (const float*)d_in[0];
    x = (const float*)d_in[1];
  }
  float* outp = (float*)d_out;
  char* ws = (char*)d_ws;

  // Early region (dead after k_level2), overlapped later by DB (33.5 MB):
  uint32_t* KA = (uint32_t*)(ws + 0);         // 4 MB
  uint32_t* KB = (uint32_t*)(ws + 4194304);   // 4 MB
  uint32_t* HIST = (uint32_t*)(ws + 8388608); // 256 KB
  int* IDX1 = (int*)(ws + 8650752);           // 4 MB -> ends 12845056
  float* DB = (float*)(ws + 0);               // 33554432 B (overlaps all above)

  // Persistent region:
  size_t P = 33554432;
  int* IDXT = (int*)(ws + P);          P += 4194304;
  float* CM = (float*)(ws + P);        P += 262144;
  int* IND0T = (int*)(ws + P);         P += 270336;
  float* C1SEL = (float*)(ws + P);     P += 270336;
  int* IND = (int*)(ws + P);           P += 131072;
  float* QB1 = (float*)(ws + P);       P += 2048;   // total ~38.7 MB

  k_keys1<<<4096, 256, 0, stream>>>(coords, KA);

  // LSD radix (values only): KA->KB->KA->KB->KA
  k_radix_hist<<<256, 256, 0, stream>>>(KA, HIST, 0);
  k_scan<<<8, 256, 0, stream>>>(HIST, 8192);
  k_radix_scatter<<<256, 256, 0, stream>>>(KA, KB, HIST, 0);
  k_radix_hist<<<256, 256, 0, stream>>>(KB, HIST, 8);
  k_scan<<<8, 256, 0, stream>>>(HIST, 8192);
  k_radix_scatter<<<256, 256, 0, stream>>>(KB, KA, HIST, 8);
  k_radix_hist<<<256, 256, 0, stream>>>(KA, HIST, 16);
  k_scan<<<8, 256, 0, stream>>>(HIST, 8192);
  k_radix_scatter<<<256, 256, 0, stream>>>(KA, KB, HIST, 16);
  k_radix_hist<<<256, 256, 0, stream>>>(KB, HIST, 24);
  k_scan<<<8, 256, 0, stream>>>(HIST, 8192);
  k_radix_scatter<<<256, 256, 0, stream>>>(KB, KA, HIST, 24);

  k_quantile1<<<8, 64, 0, stream>>>(KA, QB1);

  k_bhist<<<256, 256, 0, stream>>>(coords, QB1, HIST);
  k_scan<<<8, 256, 0, stream>>>(HIST, 2048);
  k_bscatter<<<256, 256, 0, stream>>>(coords, QB1, HIST, IDX1);

  k_level2<<<512, 256, 0, stream>>>(IDX1, coords, IDXT, CM);

  k_coordsel<<<8, 256, 0, stream>>>(CM, IND0T, C1SEL);
  k_sel1b<<<512, 64, 0, stream>>>(C1SEL, IND);

  k_db<<<4096, 256, 0, stream>>>(x, IDXT, DB);
  k_final3<<<2048, 256, 0, stream>>>(DB, IND, IND0T, outp);
}

// Round 13
// 401.449 us; speedup vs baseline: 3.4242x; 1.9397x over previous
//
#include <hip/hip_runtime.h>
#include <stdint.h>

#define NPTS 131072

// ---------- helpers (XLA:GPU contraction semantics: fma-fused) ----------

__device__ __forceinline__ float cubw(float t) {
#pragma clang fp contract(off)
  float at = fabsf(t);
  if (at <= 1.0f) {
    float u = fmaf(1.25f, at, -2.25f);
    u = u * at;
    return fmaf(u, at, 1.0f);
  } else if (at < 2.0f) {
    float u = at - 5.0f;
    u = fmaf(u, at, 8.0f);
    u = fmaf(u, at, -4.0f);
    return u * -0.75f;
  }
  return 0.0f;
}

__device__ __forceinline__ float quant_frac(int t) {
#pragma clang fp contract(off)
  return (float)(t + 1) * 0.015625f;
}

__device__ __forceinline__ float grid_val(int i) {
#pragma clang fp contract(off)
  return (float)i * (1.0f / 63.0f);
}

__device__ __forceinline__ float jax_quantile_lerp(float vlo, float vhi, float q) {
#pragma clang fp contract(off)
  float lowf = floorf(q);
  float highf = ceilf(q);
  float hw = q - lowf;
  float lw = highf - q;
  float bh = vhi * hw;
  return fmaf(vlo, lw, bh);
}

__device__ __forceinline__ float bilerp1(float a, float b, float w) {
#pragma clang fp contract(off)
  float omw = 1.0f - w;
  float bw = b * w;
  return fmaf(a, omw, bw);
}

template <int NB>
__device__ __forceinline__ unsigned long long match_mask(uint32_t d) {
  unsigned long long m = ~0ull;
#pragma unroll
  for (int i = 0; i < NB; ++i) {
    unsigned long long bal = __ballot((int)((d >> i) & 1u));
    m &= ((d >> i) & 1u) ? bal : ~bal;
  }
  return m;
}

// ---------- key building ----------

__global__ __launch_bounds__(256) void k_keys1(const float* __restrict__ coords,
                                               uint32_t* __restrict__ ka) {
#pragma clang fp contract(off)
  int i = blockIdx.x * 256 + threadIdx.x;
  int b = i >> 17, idx = i & (NPTS - 1);
  float c = coords[(size_t)(b * 2) * NPTS + idx] + (float)(8 * b);
  ka[i] = __float_as_uint(c);
}

// ---------- LSD radix sort (values only), 8 segments of 131072 ----------

__global__ __launch_bounds__(256) void k_radix_hist(const uint32_t* __restrict__ in,
                                                    uint32_t* __restrict__ hist, int shift) {
  __shared__ uint32_t h[256];
  int tid = threadIdx.x;
  int batch = blockIdx.x >> 5, blk = blockIdx.x & 31;
  h[tid] = 0;
  __syncthreads();
  const uint32_t* keys = in + (size_t)batch * NPTS + (size_t)blk * 4096;
  for (int r = 0; r < 16; ++r) {
    uint32_t d = (keys[r * 256 + tid] >> shift) & 255u;
    atomicAdd(&h[d], 1u);
  }
  __syncthreads();
  hist[((size_t)batch * 256 + tid) * 32 + blk] = h[tid];
}

__global__ __launch_bounds__(256) void k_scan(uint32_t* __restrict__ buf, int len) {
  __shared__ uint32_t tot[256];
  int batch = blockIdx.x, tid = threadIdx.x;
  int per = len >> 8;
  uint32_t* p = buf + (size_t)batch * len + (size_t)tid * per;
  uint32_t s = 0;
  for (int i = 0; i < per; ++i) s += p[i];
  tot[tid] = s;
  __syncthreads();
  if (tid == 0) {
    uint32_t run = 0;
    for (int i = 0; i < 256; ++i) { uint32_t t = tot[i]; tot[i] = run; run += t; }
  }
  __syncthreads();
  uint32_t run = tot[tid];
  for (int i = 0; i < per; ++i) { uint32_t t = p[i]; p[i] = run; run += t; }
}

__global__ __launch_bounds__(256) void k_radix_scatter(const uint32_t* __restrict__ in,
                                                       uint32_t* __restrict__ out,
                                                       const uint32_t* __restrict__ base,
                                                       int shift) {
  __shared__ uint32_t whist[4 * 256];
  int tid = threadIdx.x;
  int wv = tid >> 6, lane = tid & 63;
  int batch = blockIdx.x >> 5, blk = blockIdx.x & 31;
  size_t batchbase = (size_t)batch * NPTS;
  const uint32_t* src = in + batchbase + (size_t)blk * 4096 + (size_t)wv * 1024;

  for (int i = tid; i < 4 * 256; i += 256) whist[i] = 0;
  __syncthreads();

  uint32_t keyv[16], posv[16];
#pragma unroll
  for (int r = 0; r < 16; ++r) {
    uint32_t key = src[r * 64 + lane];
    uint32_t d = (key >> shift) & 255u;
    unsigned long long m = match_mask<8>(d);
    unsigned long long below = m & ((1ull << lane) - 1ull);
    uint32_t rank = (uint32_t)__popcll(below);
    uint32_t cnt = (uint32_t)__popcll(m);
    uint32_t bse = whist[wv * 256 + d];
    if (below == 0ull) whist[wv * 256 + d] = bse + cnt;
    keyv[r] = key;
    posv[r] = bse + rank;
  }
  __syncthreads();
  {
    uint32_t a0 = whist[tid], a1 = whist[256 + tid], a2 = whist[512 + tid];
    whist[tid] = 0;
    whist[256 + tid] = a0;
    whist[512 + tid] = a0 + a1;
    whist[768 + tid] = a0 + a1 + a2;
  }
  __syncthreads();
  const uint32_t* bb = base + (size_t)batch * 8192;
#pragma unroll
  for (int r = 0; r < 16; ++r) {
    uint32_t key = keyv[r];
    uint32_t d = (key >> shift) & 255u;
    uint32_t pos = bb[d * 32 + blk] + whist[wv * 256 + d] + posv[r];
    out[batchbase + pos] = key;
  }
}

// ---------- level-1 quantiles ----------

__global__ __launch_bounds__(64) void k_quantile1(const uint32_t* __restrict__ sorted,
                                                  float* __restrict__ qb1) {
#pragma clang fp contract(off)
  int batch = blockIdx.x, t = threadIdx.x;
  if (t >= 63) return;
  float qv = quant_frac(t);
  float q = qv * 131071.0f;
  int lo = (int)floorf(q);
  const uint32_t* s = sorted + (size_t)batch * NPTS;
  qb1[batch * 64 + t] =
      jax_quantile_lerp(__uint_as_float(s[lo]), __uint_as_float(s[lo + 1]), q);
}

// ---------- level-1 stable counting sort by bucket ----------

__global__ __launch_bounds__(256) void k_bhist(const float* __restrict__ coords,
                                               const float* __restrict__ qb1,
                                               uint32_t* __restrict__ hist) {
#pragma clang fp contract(off)
  __shared__ uint32_t h[64];
  __shared__ float qb[63];
  int tid = threadIdx.x;
  int batch = blockIdx.x >> 5, blk = blockIdx.x & 31;
  if (tid < 64) h[tid] = 0;
  if (tid >= 64 && tid < 127) qb[tid - 64] = qb1[batch * 64 + (tid - 64)];
  __syncthreads();
  const float* c = coords + (size_t)(batch * 2) * NPTS + (size_t)blk * 4096;
  float off = (float)(8 * batch);
  for (int r = 0; r < 16; ++r) {
    float v = c[r * 256 + tid] + off;
    uint32_t d = 0;
#pragma unroll
    for (int k = 0; k < 63; ++k) d += (qb[k] <= v) ? 1u : 0u;
    atomicAdd(&h[d], 1u);
  }
  __syncthreads();
  if (tid < 64) hist[((size_t)batch * 64 + tid) * 32 + blk] = h[tid];
}

__global__ __launch_bounds__(256) void k_bscatter(const float* __restrict__ coords,
                                                  const float* __restrict__ qb1,
                                                  const uint32_t* __restrict__ base,
                                                  int* __restrict__ idxout) {
#pragma clang fp contract(off)
  __shared__ uint32_t whist[4 * 64];
  __shared__ float qb[63];
  int tid = threadIdx.x;
  int wv = tid >> 6, lane = tid & 63;
  int batch = blockIdx.x >> 5, blk = blockIdx.x & 31;
  if (tid < 4 * 64) whist[tid] = 0;
  if (tid >= 192 && tid < 255) qb[tid - 192] = qb1[batch * 64 + (tid - 192)];
  __syncthreads();
  const float* c = coords + (size_t)(batch * 2) * NPTS + (size_t)blk * 4096 + (size_t)wv * 1024;
  float off = (float)(8 * batch);
  uint32_t bkv[16], rkv[16];
#pragma unroll
  for (int r = 0; r < 16; ++r) {
    float v = c[r * 64 + lane] + off;
    uint32_t d = 0;
#pragma unroll
    for (int k = 0; k < 63; ++k) d += (qb[k] <= v) ? 1u : 0u;
    unsigned long long m = match_mask<6>(d);
    unsigned long long below = m & ((1ull << lane) - 1ull);
    uint32_t rank = (uint32_t)__popcll(below);
    uint32_t cnt = (uint32_t)__popcll(m);
    uint32_t bse = whist[wv * 64 + d];
    if (below == 0ull) whist[wv * 64 + d] = bse + cnt;
    bkv[r] = d;
    rkv[r] = bse + rank;
  }
  __syncthreads();
  if (tid < 64) {
    uint32_t a0 = whist[tid], a1 = whist[64 + tid], a2 = whist[128 + tid];
    whist[tid] = 0;
    whist[64 + tid] = a0;
    whist[128 + tid] = a0 + a1;
    whist[192 + tid] = a0 + a1 + a2;
  }
  __syncthreads();
  const uint32_t* bb = base + (size_t)batch * 2048;
  int ibase = blk * 4096 + wv * 1024;
#pragma unroll
  for (int r = 0; r < 16; ++r) {
    uint32_t d = bkv[r];
    uint32_t pos = bb[d * 32 + blk] + whist[wv * 64 + d] + rkv[r];
    idxout[(size_t)batch * NPTS + pos] = ibase + r * 64 + lane;
  }
}

// ---------- level-2 ----------

#define BITONIC2048(arr)                                      \
  for (int k = 2; k <= 2048; k <<= 1) {                       \
    for (int j = k >> 1; j > 0; j >>= 1) {                    \
      for (int i = tid; i < 2048; i += 256) {                 \
        int ixj = i ^ j;                                      \
        if (ixj > i) {                                        \
          uint32_t a = arr[i], c2 = arr[ixj];                 \
          bool up = ((i & k) == 0);                           \
          if ((a > c2) == up) { arr[i] = c2; arr[ixj] = a; }  \
        }                                                     \
      }                                                       \
      __syncthreads();                                        \
    }                                                         \
  }

__global__ __launch_bounds__(256) void k_level2(const int* __restrict__ idx1,
                                                const float* __restrict__ coords,
                                                int* __restrict__ idxT,
                                                float* __restrict__ cm) {
#pragma clang fp contract(off)
  __shared__ int gidx[2048];
  __shared__ float ckey[2048];
  __shared__ uint32_t sb[2048];
  __shared__ float qb[63];

  const int tid = threadIdx.x;
  const int row = blockIdx.x;
  const int b = row >> 6, i1 = row & 63;
  const float offf = (float)(512 * row);

  for (int j = tid; j < 2048; j += 256) {
    int g = idx1[(size_t)b * NPTS + i1 * 2048 + j];
    gidx[j] = g;
    float cv = coords[((size_t)(b * 2 + 1)) * NPTS + g] + offf;
    ckey[j] = cv;
    sb[j] = __float_as_uint(cv);
  }
  __syncthreads();

  BITONIC2048(sb)

  if (tid < 63) {
    float qv = quant_frac(tid);
    float q = qv * 2047.0f;
    int lo = (int)floorf(q);
    qb[tid] = jax_quantile_lerp(__uint_as_float(sb[lo]), __uint_as_float(sb[lo + 1]), q);
  }
  __syncthreads();

  for (int j = tid; j < 2048; j += 256) {
    float cv = ckey[j];
    uint32_t d = 0;
#pragma unroll
    for (int k = 0; k < 63; ++k) d += (qb[k] <= cv) ? 1u : 0u;
    sb[j] = (d << 11) | (uint32_t)j;
  }
  __syncthreads();

  BITONIC2048(sb)

  for (int p = tid; p < 2048; p += 256)
    idxT[(size_t)b * NPTS + i1 * 2048 + p] = gidx[sb[p] & 0x7FFu];

  if (tid < 128) {
    int i2 = tid >> 1, d = tid & 1;
    float v[32];
#pragma unroll
    for (int m2 = 0; m2 < 32; ++m2)
      v[m2] = coords[((size_t)(b * 2 + d)) * NPTS + gidx[sb[i2 * 32 + m2] & 0x7FFu]];
#pragma unroll
    for (int r = 0; r < 32; ++r) {
#pragma unroll
      for (int i = (r & 1); i + 1 < 32; i += 2) {
        float a = v[i], c2 = v[i + 1];
        v[i] = fminf(a, c2);
        v[i + 1] = fmaxf(a, c2);
      }
    }
    cm[(((size_t)(b * 2 + d)) * 64 + i1) * 64 + i2] = v[15];
  }
}

// ---------- padded coord grid CP[b*2+d][66][66] (same arithmetic as fused) ----------

__global__ __launch_bounds__(256) void k_cp2(const float* __restrict__ cm,
                                             float* __restrict__ cp) {
#pragma clang fp contract(off)
  __shared__ float cp0[66][66];
  __shared__ float cp1[66][66];
  const int b = blockIdx.x;
  const int tid = threadIdx.x;
  const float* m0 = cm + (size_t)(b * 2) * 4096;
  const float* m1 = cm + (size_t)(b * 2 + 1) * 4096;

  for (int i = tid; i < 4096; i += 256) {
    int i1 = i >> 6, i2 = i & 63;
    cp0[1 + i1][1 + i2] = m0[i];
    cp1[1 + i1][1 + i2] = m1[i];
  }
  __syncthreads();

  if (tid < 64) {
    int i2 = tid;
    float mn = m0[i2], mx = m0[i2];
    for (int i1 = 1; i1 < 64; ++i1) {
      float v = m0[i1 * 64 + i2];
      mn = fminf(mn, v);
      mx = fmaxf(mx, v);
    }
    cp0[0][1 + i2] = mn - 0.5f;
    cp0[65][1 + i2] = mx + 0.5f;
  } else if (tid < 128) {
    int i1 = tid - 64;
    float mn = m1[i1 * 64], mx = m1[i1 * 64];
    for (int i2 = 1; i2 < 64; ++i2) {
      float v = m1[i1 * 64 + i2];
      mn = fminf(mn, v);
      mx = fmaxf(mx, v);
    }
    cp1[1 + i1][0] = mn - 0.5f;
    cp1[1 + i1][65] = mx + 0.5f;
  }
  __syncthreads();

  if (tid < 66) {
    cp0[tid][0] = cp0[tid][1];
    cp0[tid][65] = cp0[tid][64];
  } else if (tid < 132) {
    int w = tid - 66;
    cp1[0][w] = cp1[1][w];
    cp1[65][w] = cp1[64][w];
  }
  __syncthreads();

  for (int e = tid; e < 4356; e += 256) {
    int h = e / 66, w = e % 66;
    cp[((size_t)(b * 2) * 66 + h) * 66 + w] = cp0[h][w];
    cp[((size_t)(b * 2 + 1) * 66 + h) * 66 + w] = cp1[h][w];
  }
}

// ---------- H-pass bilinear: TH[bd][132][66] ----------

__global__ __launch_bounds__(256) void k_th(const float* __restrict__ cp,
                                            float* __restrict__ th) {
#pragma clang fp contract(off)
  int e = blockIdx.x * 256 + threadIdx.x;
  if (e >= 16 * 132 * 66) return;
  int w = e % 66;
  int rest = e / 66;
  int hp = rest % 132;
  int bd = rest / 132;
  const float R = (float)(65.0 / 131.0);
  float pos = (float)hp * R;
  int r0 = (int)floorf(pos);
  if (r0 < 0) r0 = 0;
  if (r0 > 65) r0 = 65;
  int r1 = r0 + 1;
  if (r1 > 65) r1 = 65;
  float wt = pos - (float)r0;
  const float* p = cp + (size_t)bd * 66 * 66;
  th[((size_t)bd * 132 + hp) * 66 + w] = bilerp1(p[r0 * 66 + w], p[r1 * 66 + w], wt);
}

// ---------- W-pass bilinear: CI[bd][132][132] ----------

__global__ __launch_bounds__(256) void k_ci(const float* __restrict__ th,
                                            float* __restrict__ ci) {
#pragma clang fp contract(off)
  int e = blockIdx.x * 256 + threadIdx.x;
  if (e >= 16 * 132 * 132) return;
  int wp = e % 132;
  int rest = e / 132;
  int hp = rest % 132;
  int bd = rest / 132;
  const float R = (float)(65.0 / 131.0);
  float pos = (float)wp * R;
  int j0 = (int)floorf(pos);
  if (j0 < 0) j0 = 0;
  if (j0 > 65) j0 = 65;
  int j1 = j0 + 1;
  if (j1 > 65) j1 = 65;
  float wu = pos - (float)j0;
  const float* t = th + (size_t)bd * 132 * 66;
  ci[((size_t)bd * 132 + hp) * 132 + wp] =
      bilerp1(t[hp * 66 + j0], t[hp * 66 + j1], wu);
}

// ---------- argmin over h per (b,w): ind0t, c1sel ----------

__global__ __launch_bounds__(128) void k_sel0(const float* __restrict__ ci,
                                              int* __restrict__ ind0t,
                                              float* __restrict__ c1sel) {
#pragma clang fp contract(off)
  __shared__ float col0[132], col1[132];
  int bw = blockIdx.x;
  int b = bw / 132, w = bw % 132;
  int tid = threadIdx.x;
  for (int h = tid; h < 132; h += 128) {
    col0[h] = ci[((size_t)(b * 2) * 132 + h) * 132 + w];
    col1[h] = ci[((size_t)(b * 2 + 1) * 132 + h) * 132 + w];
  }
  __syncthreads();
  if (tid < 64) {
    float gv = grid_val(tid);
    float best = fabsf(col0[0] - gv);
    int bi = 0;
    for (int h = 1; h < 132; ++h) {
      float d2 = fabsf(col0[h] - gv);
      if (d2 < best) { best = d2; bi = h; }
    }
    ind0t[((size_t)b * 64 + tid) * 132 + w] = bi;
    c1sel[((size_t)b * 64 + tid) * 132 + w] = col1[bi];
  }
}

__global__ __launch_bounds__(64) void k_sel1b(const float* __restrict__ c1sel,
                                              int* __restrict__ ind) {
#pragma clang fp contract(off)
  __shared__ float rv[132];
  int b = blockIdx.x >> 6, g0 = blockIdx.x & 63;
  int tid = threadIdx.x;
  for (int w = tid; w < 132; w += 64) rv[w] = c1sel[((size_t)b * 64 + g0) * 132 + w];
  __syncthreads();
  float gv = grid_val(tid);
  float best = fabsf(rv[0] - gv);
  int bi = 0;
  for (int w = 1; w < 132; ++w) {
    float d2 = fabsf(rv[w] - gv);
    if (d2 < best) { best = d2; bi = w; }
  }
  ind[((size_t)b * 64 + g0) * 64 + tid] = bi;
}

// ---------- gather x into cell-contiguous DB[b*4096+cell][256] ----------

__global__ __launch_bounds__(256) void k_db(const float* __restrict__ x,
                                            const int* __restrict__ idxT,
                                            float* __restrict__ db) {
  int t = blockIdx.x * 256 + threadIdx.x;
  int mi = t & 31;
  int cellLocal = (t >> 5) & 4095;
  int b = t >> 17;
  int g = idxT[(size_t)b * NPTS + cellLocal * 32 + mi];
  const float* src = x + ((size_t)b * NPTS + g) * 8;
  float4 lo = *(const float4*)(src);
  float4 hi = *(const float4*)(src + 4);
  float* dst = db + (size_t)t * 8;
  *(float4*)(dst) = lo;
  *(float4*)(dst + 4) = hi;
}

// ---------- final bicubic: lanes=channels, LDS transpose ----------

__global__ __launch_bounds__(256) void k_final3(const float* __restrict__ db,
                                                const int* __restrict__ ind,
                                                const int* __restrict__ ind0t,
                                                float* __restrict__ outp) {
#pragma clang fp contract(off)
  __shared__ int sRI[256], sCI[256];
  __shared__ float sWH[256], sWW[256];
  __shared__ float tile[64][65];

  const int bid = blockIdx.x;
  const int b = bid >> 8;
  const int p = (bid >> 2) & 63;
  const int cg = bid & 3;
  const int tid = threadIdx.x;
  const float R = (float)(65.0 / 131.0);

  if (tid < 64) {
    int qt = tid;
    int wstar = ind[((size_t)b * 64 + qt) * 64 + p];
    int hstar = ind0t[((size_t)b * 64 + qt) * 132 + wstar];
    float posh = (float)hstar * R;
    int i0h = (int)floorf(posh);
    float frh = posh - (float)i0h;
    float posw = (float)wstar * R;
    int i0w = (int)floorf(posw);
    float frw = posw - (float)i0w;
#pragma unroll
    for (int k = 0; k < 4; ++k) {
      int I = i0h + k - 1;
      I = I < 0 ? 0 : (I > 65 ? 65 : I);
      int rI = I - 1;
      sRI[qt * 4 + k] = rI < 0 ? 0 : (rI > 63 ? 63 : rI);
      sWH[qt * 4 + k] = cubw(frh - (float)(k - 1));
      int J = i0w + k - 1;
      J = J < 0 ? 0 : (J > 65 ? 65 : J);
      int cJ = J - 1;
      sCI[qt * 4 + k] = cJ < 0 ? 0 : (cJ > 63 ? 63 : cJ);
      sWW[qt * 4 + k] = cubw(frw - (float)(k - 1));
    }
  }
  __syncthreads();

  const int wave = tid >> 6, lane = tid & 63;
  const int ch = cg * 64 + lane;
  const size_t dbb = (size_t)(b * 4096) * 256 + ch;

  for (int s = 0; s < 16; ++s) {
    int qt = wave * 16 + s;
    float a = 0.0f;
#pragma unroll
    for (int l = 0; l < 4; ++l) {
      float t = 0.0f;
#pragma unroll
      for (int k = 0; k < 4; ++k) {
        float v = db[dbb + (size_t)(sRI[qt * 4 + k] * 64 + sCI[qt * 4 + l]) * 256];
        t = fmaf(v, sWH[qt * 4 + k], t);
      }
      a = fmaf(t, sWW[qt * 4 + l], a);
    }
    tile[qt][lane] = a;
  }
  __syncthreads();

  for (int it = 0; it < 16; ++it) {
    int qt2 = tid & 63;
    int cc = (tid >> 6) * 16 + it;
    outp[(((size_t)b * 256 + cg * 64 + cc) * 64 + p) * 64 + qt2] = tile[qt2][cc];
  }
}

// ---------- launch ----------

extern "C" void kernel_launch(void* const* d_in, const int* in_sizes, int n_in,
                              void* d_out, int out_size, void* d_ws, size_t ws_size,
                              hipStream_t stream) {
  (void)n_in; (void)out_size; (void)ws_size;
  const float* x;
  const float* coords;
  if (in_sizes[0] == 8388608) {
    x = (const float*)d_in[0];
    coords = (const float*)d_in[1];
  } else {
    coords = (const float*)d_in[0];
    x = (const float*)d_in[1];
  }
  float* outp = (float*)d_out;
  char* ws = (char*)d_ws;

  // Early region A (dead after k_level2): radix buffers
  uint32_t* KA = (uint32_t*)(ws + 0);         // 4 MB
  uint32_t* KB = (uint32_t*)(ws + 4194304);   // 4 MB
  uint32_t* HIST = (uint32_t*)(ws + 8388608); // 256 KB
  int* IDX1 = (int*)(ws + 8650752);           // 4 MB -> ends 12845056
  // Early region B (written after k_level2, dead before k_db): coord chain
  float* CP = (float*)(ws + 0);               // 278784 B
  float* TH = (float*)(ws + 279040);          // 557568 B
  float* CI = (float*)(ws + 836864);          // 1115136 B -> ends 1952000
  // DB overlaps all early regions (written after CI consumed)
  float* DB = (float*)(ws + 0);               // 33554432 B

  // Persistent region:
  size_t P = 33554432;
  int* IDXT = (int*)(ws + P);          P += 4194304;
  float* CM = (float*)(ws + P);        P += 262144;
  int* IND0T = (int*)(ws + P);         P += 270336;
  float* C1SEL = (float*)(ws + P);     P += 270336;
  int* IND = (int*)(ws + P);           P += 131072;
  float* QB1 = (float*)(ws + P);       P += 2048;

  k_keys1<<<4096, 256, 0, stream>>>(coords, KA);

  k_radix_hist<<<256, 256, 0, stream>>>(KA, HIST, 0);
  k_scan<<<8, 256, 0, stream>>>(HIST, 8192);
  k_radix_scatter<<<256, 256, 0, stream>>>(KA, KB, HIST, 0);
  k_radix_hist<<<256, 256, 0, stream>>>(KB, HIST, 8);
  k_scan<<<8, 256, 0, stream>>>(HIST, 8192);
  k_radix_scatter<<<256, 256, 0, stream>>>(KB, KA, HIST, 8);
  k_radix_hist<<<256, 256, 0, stream>>>(KA, HIST, 16);
  k_scan<<<8, 256, 0, stream>>>(HIST, 8192);
  k_radix_scatter<<<256, 256, 0, stream>>>(KA, KB, HIST, 16);
  k_radix_hist<<<256, 256, 0, stream>>>(KB, HIST, 24);
  k_scan<<<8, 256, 0, stream>>>(HIST, 8192);
  k_radix_scatter<<<256, 256, 0, stream>>>(KB, KA, HIST, 24);

  k_quantile1<<<8, 64, 0, stream>>>(KA, QB1);

  k_bhist<<<256, 256, 0, stream>>>(coords, QB1, HIST);
  k_scan<<<8, 256, 0, stream>>>(HIST, 2048);
  k_bscatter<<<256, 256, 0, stream>>>(coords, QB1, HIST, IDX1);

  k_level2<<<512, 256, 0, stream>>>(IDX1, coords, IDXT, CM);

  k_cp2<<<8, 256, 0, stream>>>(CM, CP);
  k_th<<<545, 256, 0, stream>>>(CP, TH);
  k_ci<<<1089, 256, 0, stream>>>(TH, CI);
  k_sel0<<<1056, 128, 0, stream>>>(CI, IND0T, C1SEL);
  k_sel1b<<<512, 64, 0, stream>>>(C1SEL, IND);

  k_db<<<4096, 256, 0, stream>>>(x, IDXT, DB);
  k_final3<<<2048, 256, 0, stream>>>(DB, IND, IND0T, outp);
}

// Round 14
// 300.133 us; speedup vs baseline: 4.5801x; 1.3376x over previous
//
#include <hip/hip_runtime.h>
#include <stdint.h>

#define NPTS 131072

// ---------- helpers (XLA:GPU contraction semantics: fma-fused) ----------

__device__ __forceinline__ float cubw(float t) {
#pragma clang fp contract(off)
  float at = fabsf(t);
  if (at <= 1.0f) {
    float u = fmaf(1.25f, at, -2.25f);
    u = u * at;
    return fmaf(u, at, 1.0f);
  } else if (at < 2.0f) {
    float u = at - 5.0f;
    u = fmaf(u, at, 8.0f);
    u = fmaf(u, at, -4.0f);
    return u * -0.75f;
  }
  return 0.0f;
}

__device__ __forceinline__ float quant_frac(int t) {
#pragma clang fp contract(off)
  return (float)(t + 1) * 0.015625f;
}

__device__ __forceinline__ float grid_val(int i) {
#pragma clang fp contract(off)
  return (float)i * (1.0f / 63.0f);
}

__device__ __forceinline__ float jax_quantile_lerp(float vlo, float vhi, float q) {
#pragma clang fp contract(off)
  float lowf = floorf(q);
  float highf = ceilf(q);
  float hw = q - lowf;
  float lw = highf - q;
  float bh = vhi * hw;
  return fmaf(vlo, lw, bh);
}

__device__ __forceinline__ float bilerp1(float a, float b, float w) {
#pragma clang fp contract(off)
  float omw = 1.0f - w;
  float bw = b * w;
  return fmaf(a, omw, bw);
}

template <int NB>
__device__ __forceinline__ unsigned long long match_mask(uint32_t d) {
  unsigned long long m = ~0ull;
#pragma unroll
  for (int i = 0; i < NB; ++i) {
    unsigned long long bal = __ballot((int)((d >> i) & 1u));
    m &= ((d >> i) & 1u) ? bal : ~bal;
  }
  return m;
}

// ---------- key building ----------

__global__ __launch_bounds__(256) void k_keys1(const float* __restrict__ coords,
                                               uint32_t* __restrict__ ka) {
#pragma clang fp contract(off)
  int i = blockIdx.x * 256 + threadIdx.x;
  int b = i >> 17, idx = i & (NPTS - 1);
  float c = coords[(size_t)(b * 2) * NPTS + idx] + (float)(8 * b);
  ka[i] = __float_as_uint(c);
}

// ---------- LSD radix sort (values only), 8 segments of 131072 ----------

__global__ __launch_bounds__(256) void k_radix_hist(const uint32_t* __restrict__ in,
                                                    uint32_t* __restrict__ hist, int shift) {
  __shared__ uint32_t h[256];
  int tid = threadIdx.x;
  int batch = blockIdx.x >> 5, blk = blockIdx.x & 31;
  h[tid] = 0;
  __syncthreads();
  const uint32_t* keys = in + (size_t)batch * NPTS + (size_t)blk * 4096;
  for (int r = 0; r < 16; ++r) {
    uint32_t d = (keys[r * 256 + tid] >> shift) & 255u;
    atomicAdd(&h[d], 1u);
  }
  __syncthreads();
  hist[((size_t)batch * 256 + tid) * 32 + blk] = h[tid];
}

__global__ __launch_bounds__(256) void k_scan(uint32_t* __restrict__ buf, int len) {
  __shared__ uint32_t tot[256];
  int batch = blockIdx.x, tid = threadIdx.x;
  int per = len >> 8;
  uint32_t* p = buf + (size_t)batch * len + (size_t)tid * per;
  uint32_t s = 0;
  for (int i = 0; i < per; ++i) s += p[i];
  tot[tid] = s;
  __syncthreads();
  if (tid == 0) {
    uint32_t run = 0;
    for (int i = 0; i < 256; ++i) { uint32_t t = tot[i]; tot[i] = run; run += t; }
  }
  __syncthreads();
  uint32_t run = tot[tid];
  for (int i = 0; i < per; ++i) { uint32_t t = p[i]; p[i] = run; run += t; }
}

__global__ __launch_bounds__(256) void k_radix_scatter(const uint32_t* __restrict__ in,
                                                       uint32_t* __restrict__ out,
                                                       const uint32_t* __restrict__ base,
                                                       int shift) {
  __shared__ uint32_t whist[4 * 256];
  int tid = threadIdx.x;
  int wv = tid >> 6, lane = tid & 63;
  int batch = blockIdx.x >> 5, blk = blockIdx.x & 31;
  size_t batchbase = (size_t)batch * NPTS;
  const uint32_t* src = in + batchbase + (size_t)blk * 4096 + (size_t)wv * 1024;

  for (int i = tid; i < 4 * 256; i += 256) whist[i] = 0;
  __syncthreads();

  uint32_t keyv[16], posv[16];
#pragma unroll
  for (int r = 0; r < 16; ++r) {
    uint32_t key = src[r * 64 + lane];
    uint32_t d = (key >> shift) & 255u;
    unsigned long long m = match_mask<8>(d);
    unsigned long long below = m & ((1ull << lane) - 1ull);
    uint32_t rank = (uint32_t)__popcll(below);
    uint32_t cnt = (uint32_t)__popcll(m);
    uint32_t bse = whist[wv * 256 + d];
    if (below == 0ull) whist[wv * 256 + d] = bse + cnt;
    keyv[r] = key;
    posv[r] = bse + rank;
  }
  __syncthreads();
  {
    uint32_t a0 = whist[tid], a1 = whist[256 + tid], a2 = whist[512 + tid];
    whist[tid] = 0;
    whist[256 + tid] = a0;
    whist[512 + tid] = a0 + a1;
    whist[768 + tid] = a0 + a1 + a2;
  }
  __syncthreads();
  const uint32_t* bb = base + (size_t)batch * 8192;
#pragma unroll
  for (int r = 0; r < 16; ++r) {
    uint32_t key = keyv[r];
    uint32_t d = (key >> shift) & 255u;
    uint32_t pos = bb[d * 32 + blk] + whist[wv * 256 + d] + posv[r];
    out[batchbase + pos] = key;
  }
}

// ---------- level-1 quantiles ----------

__global__ __launch_bounds__(64) void k_quantile1(const uint32_t* __restrict__ sorted,
                                                  float* __restrict__ qb1) {
#pragma clang fp contract(off)
  int batch = blockIdx.x, t = threadIdx.x;
  if (t >= 63) return;
  float qv = quant_frac(t);
  float q = qv * 131071.0f;
  int lo = (int)floorf(q);
  const uint32_t* s = sorted + (size_t)batch * NPTS;
  qb1[batch * 64 + t] =
      jax_quantile_lerp(__uint_as_float(s[lo]), __uint_as_float(s[lo + 1]), q);
}

// ---------- level-1 stable counting sort by bucket ----------

__global__ __launch_bounds__(256) void k_bhist(const float* __restrict__ coords,
                                               const float* __restrict__ qb1,
                                               uint32_t* __restrict__ hist) {
#pragma clang fp contract(off)
  __shared__ uint32_t h[64];
  __shared__ float qb[63];
  int tid = threadIdx.x;
  int batch = blockIdx.x >> 5, blk = blockIdx.x & 31;
  if (tid < 64) h[tid] = 0;
  if (tid >= 64 && tid < 127) qb[tid - 64] = qb1[batch * 64 + (tid - 64)];
  __syncthreads();
  const float* c = coords + (size_t)(batch * 2) * NPTS + (size_t)blk * 4096;
  float off = (float)(8 * batch);
  for (int r = 0; r < 16; ++r) {
    float v = c[r * 256 + tid] + off;
    uint32_t d = 0;
#pragma unroll
    for (int k = 0; k < 63; ++k) d += (qb[k] <= v) ? 1u : 0u;
    atomicAdd(&h[d], 1u);
  }
  __syncthreads();
  if (tid < 64) hist[((size_t)batch * 64 + tid) * 32 + blk] = h[tid];
}

__global__ __launch_bounds__(256) void k_bscatter(const float* __restrict__ coords,
                                                  const float* __restrict__ qb1,
                                                  const uint32_t* __restrict__ base,
                                                  int* __restrict__ idxout) {
#pragma clang fp contract(off)
  __shared__ uint32_t whist[4 * 64];
  __shared__ float qb[63];
  int tid = threadIdx.x;
  int wv = tid >> 6, lane = tid & 63;
  int batch = blockIdx.x >> 5, blk = blockIdx.x & 31;
  if (tid < 4 * 64) whist[tid] = 0;
  if (tid >= 192 && tid < 255) qb[tid - 192] = qb1[batch * 64 + (tid - 192)];
  __syncthreads();
  const float* c = coords + (size_t)(batch * 2) * NPTS + (size_t)blk * 4096 + (size_t)wv * 1024;
  float off = (float)(8 * batch);
  uint32_t bkv[16], rkv[16];
#pragma unroll
  for (int r = 0; r < 16; ++r) {
    float v = c[r * 64 + lane] + off;
    uint32_t d = 0;
#pragma unroll
    for (int k = 0; k < 63; ++k) d += (qb[k] <= v) ? 1u : 0u;
    unsigned long long m = match_mask<6>(d);
    unsigned long long below = m & ((1ull << lane) - 1ull);
    uint32_t rank = (uint32_t)__popcll(below);
    uint32_t cnt = (uint32_t)__popcll(m);
    uint32_t bse = whist[wv * 64 + d];
    if (below == 0ull) whist[wv * 64 + d] = bse + cnt;
    bkv[r] = d;
    rkv[r] = bse + rank;
  }
  __syncthreads();
  if (tid < 64) {
    uint32_t a0 = whist[tid], a1 = whist[64 + tid], a2 = whist[128 + tid];
    whist[tid] = 0;
    whist[64 + tid] = a0;
    whist[128 + tid] = a0 + a1;
    whist[192 + tid] = a0 + a1 + a2;
  }
  __syncthreads();
  const uint32_t* bb = base + (size_t)batch * 2048;
  int ibase = blk * 4096 + wv * 1024;
#pragma unroll
  for (int r = 0; r < 16; ++r) {
    uint32_t d = bkv[r];
    uint32_t pos = bb[d * 32 + blk] + whist[wv * 64 + d] + rkv[r];
    idxout[(size_t)batch * NPTS + pos] = ibase + r * 64 + lane;
  }
}

// ---------- level-2: ballot-radix value sort + ballot counting bucket sort ----------

__global__ __launch_bounds__(256) void k_level2(const int* __restrict__ idx1,
                                                const float* __restrict__ coords,
                                                int* __restrict__ idxT,
                                                float* __restrict__ cm) {
#pragma clang fp contract(off)
  __shared__ int gidx[2048];
  __shared__ float ckey[2048];
  __shared__ uint32_t sbA[2048];
  __shared__ uint32_t sbB[2048];
  __shared__ uint32_t whist[4 * 256];
  __shared__ uint32_t base[256];
  __shared__ uint32_t wavetot[4];
  __shared__ float qb[63];

  const int tid = threadIdx.x;
  const int wv = tid >> 6, lane = tid & 63;
  const int row = blockIdx.x;
  const int b = row >> 6, i1 = row & 63;
  const float offf = (float)(512 * row);

  for (int j = tid; j < 2048; j += 256) {
    int g = idx1[(size_t)b * NPTS + i1 * 2048 + j];
    gidx[j] = g;
    float cv = coords[((size_t)(b * 2 + 1)) * NPTS + g] + offf;
    ckey[j] = cv;
    sbA[j] = __float_as_uint(cv);  // >= 0 -> bit order == value order
  }
  __syncthreads();

  // 4-pass LSD radix value sort: sbA -> sbB -> sbA -> sbB -> sbA
  uint32_t* A = sbA;
  uint32_t* B = sbB;
  for (int pass = 0; pass < 4; ++pass) {
    const int shift = pass * 8;
    for (int i = tid; i < 1024; i += 256) whist[i] = 0;
    __syncthreads();
    uint32_t keyv[8], posv[8];
#pragma unroll
    for (int r = 0; r < 8; ++r) {
      int j = wv * 512 + r * 64 + lane;
      uint32_t key = A[j];
      uint32_t d = (key >> shift) & 255u;
      unsigned long long m = match_mask<8>(d);
      unsigned long long below = m & ((1ull << lane) - 1ull);
      uint32_t rank = (uint32_t)__popcll(below);
      uint32_t cnt = (uint32_t)__popcll(m);
      uint32_t bse = whist[wv * 256 + d];
      if (below == 0ull) whist[wv * 256 + d] = bse + cnt;
      keyv[r] = key;
      posv[r] = bse + rank;
    }
    __syncthreads();
    {
      uint32_t a0 = whist[tid], a1 = whist[256 + tid], a2 = whist[512 + tid],
               a3 = whist[768 + tid];
      base[tid] = a0 + a1 + a2 + a3;
      whist[tid] = 0;
      whist[256 + tid] = a0;
      whist[512 + tid] = a0 + a1;
      whist[768 + tid] = a0 + a1 + a2;
    }
    __syncthreads();
    {
      // exclusive scan of base[256]: per-wave shfl scan (bins tid==wv*64+lane)
      uint32_t v = base[tid];
      uint32_t inc = v;
#pragma unroll
      for (int d2 = 1; d2 < 64; d2 <<= 1) {
        uint32_t u = __shfl_up(inc, d2, 64);
        if (lane >= d2) inc += u;
      }
      if (lane == 63) wavetot[wv] = inc;
      __syncthreads();
      uint32_t woff = 0;
      for (int w2 = 0; w2 < wv; ++w2) woff += wavetot[w2];
      base[tid] = inc - v + woff;
    }
    __syncthreads();
#pragma unroll
    for (int r = 0; r < 8; ++r) {
      uint32_t d = (keyv[r] >> shift) & 255u;
      B[base[d] + whist[wv * 256 + d] + posv[r]] = keyv[r];
    }
    __syncthreads();
    uint32_t* t = A;
    A = B;
    B = t;
  }
  // sorted values now in sbA (A == sbA after 4 swaps)

  if (tid < 63) {
    float qv = quant_frac(tid);
    float q = qv * 2047.0f;
    int lo = (int)floorf(q);
    qb[tid] = jax_quantile_lerp(__uint_as_float(sbA[lo]), __uint_as_float(sbA[lo + 1]), q);
  }
  for (int i = tid; i < 256; i += 256) whist[i] = 0;  // 4*64 bins
  __syncthreads();

  // stable counting sort by bucket (j order), perm into sbB
  uint32_t dv[8], pv[8];
#pragma unroll
  for (int r = 0; r < 8; ++r) {
    int j = wv * 512 + r * 64 + lane;
    float cv = ckey[j];
    uint32_t d = 0;
#pragma unroll
    for (int k = 0; k < 63; ++k) d += (qb[k] <= cv) ? 1u : 0u;
    unsigned long long m = match_mask<6>(d);
    unsigned long long below = m & ((1ull << lane) - 1ull);
    uint32_t rank = (uint32_t)__popcll(below);
    uint32_t cnt = (uint32_t)__popcll(m);
    uint32_t bse = whist[wv * 64 + d];
    if (below == 0ull) whist[wv * 64 + d] = bse + cnt;
    dv[r] = d;
    pv[r] = bse + rank;
  }
  __syncthreads();
  if (tid < 64) {
    uint32_t a0 = whist[tid], a1 = whist[64 + tid], a2 = whist[128 + tid],
             a3 = whist[192 + tid];
    base[tid] = a0 + a1 + a2 + a3;
    whist[tid] = 0;
    whist[64 + tid] = a0;
    whist[128 + tid] = a0 + a1;
    whist[192 + tid] = a0 + a1 + a2;
  }
  __syncthreads();
  if (wv == 0) {
    uint32_t v = base[lane];
    uint32_t inc = v;
#pragma unroll
    for (int d2 = 1; d2 < 64; d2 <<= 1) {
      uint32_t u = __shfl_up(inc, d2, 64);
      if (lane >= d2) inc += u;
    }
    base[lane] = inc - v;
  }
  __syncthreads();
#pragma unroll
  for (int r = 0; r < 8; ++r) {
    int j = wv * 512 + r * 64 + lane;
    uint32_t pos = base[dv[r]] + whist[wv * 64 + dv[r]] + pv[r];
    sbB[pos] = (uint32_t)j;
  }
  __syncthreads();

  for (int p = tid; p < 2048; p += 256)
    idxT[(size_t)b * NPTS + i1 * 2048 + p] = gidx[sbB[p]];

  if (tid < 128) {
    int i2 = tid >> 1, d = tid & 1;
    float v[32];
#pragma unroll
    for (int m2 = 0; m2 < 32; ++m2)
      v[m2] = coords[((size_t)(b * 2 + d)) * NPTS + gidx[sbB[i2 * 32 + m2]]];
#pragma unroll
    for (int r = 0; r < 32; ++r) {
#pragma unroll
      for (int i = (r & 1); i + 1 < 32; i += 2) {
        float a = v[i], c2 = v[i + 1];
        v[i] = fminf(a, c2);
        v[i + 1] = fmaxf(a, c2);
      }
    }
    cm[(((size_t)(b * 2 + d)) * 64 + i1) * 64 + i2] = v[15];
  }
}

// ---------- padded coord grid CP[b*2+d][66][66] ----------

__global__ __launch_bounds__(256) void k_cp2(const float* __restrict__ cm,
                                             float* __restrict__ cp) {
#pragma clang fp contract(off)
  __shared__ float cp0[66][66];
  __shared__ float cp1[66][66];
  const int b = blockIdx.x;
  const int tid = threadIdx.x;
  const float* m0 = cm + (size_t)(b * 2) * 4096;
  const float* m1 = cm + (size_t)(b * 2 + 1) * 4096;

  for (int i = tid; i < 4096; i += 256) {
    int i1 = i >> 6, i2 = i & 63;
    cp0[1 + i1][1 + i2] = m0[i];
    cp1[1 + i1][1 + i2] = m1[i];
  }
  __syncthreads();

  if (tid < 64) {
    int i2 = tid;
    float mn = m0[i2], mx = m0[i2];
    for (int i1 = 1; i1 < 64; ++i1) {
      float v = m0[i1 * 64 + i2];
      mn = fminf(mn, v);
      mx = fmaxf(mx, v);
    }
    cp0[0][1 + i2] = mn - 0.5f;
    cp0[65][1 + i2] = mx + 0.5f;
  } else if (tid < 128) {
    int i1 = tid - 64;
    float mn = m1[i1 * 64], mx = m1[i1 * 64];
    for (int i2 = 1; i2 < 64; ++i2) {
      float v = m1[i1 * 64 + i2];
      mn = fminf(mn, v);
      mx = fmaxf(mx, v);
    }
    cp1[1 + i1][0] = mn - 0.5f;
    cp1[1 + i1][65] = mx + 0.5f;
  }
  __syncthreads();

  if (tid < 66) {
    cp0[tid][0] = cp0[tid][1];
    cp0[tid][65] = cp0[tid][64];
  } else if (tid < 132) {
    int w = tid - 66;
    cp1[0][w] = cp1[1][w];
    cp1[65][w] = cp1[64][w];
  }
  __syncthreads();

  for (int e = tid; e < 4356; e += 256) {
    int h = e / 66, w = e % 66;
    cp[((size_t)(b * 2) * 66 + h) * 66 + w] = cp0[h][w];
    cp[((size_t)(b * 2 + 1) * 66 + h) * 66 + w] = cp1[h][w];
  }
}

// ---------- H-pass bilinear ----------

__global__ __launch_bounds__(256) void k_th(const float* __restrict__ cp,
                                            float* __restrict__ th) {
#pragma clang fp contract(off)
  int e = blockIdx.x * 256 + threadIdx.x;
  if (e >= 16 * 132 * 66) return;
  int w = e % 66;
  int rest = e / 66;
  int hp = rest % 132;
  int bd = rest / 132;
  const float R = (float)(65.0 / 131.0);
  float pos = (float)hp * R;
  int r0 = (int)floorf(pos);
  if (r0 < 0) r0 = 0;
  if (r0 > 65) r0 = 65;
  int r1 = r0 + 1;
  if (r1 > 65) r1 = 65;
  float wt = pos - (float)r0;
  const float* p = cp + (size_t)bd * 66 * 66;
  th[((size_t)bd * 132 + hp) * 66 + w] = bilerp1(p[r0 * 66 + w], p[r1 * 66 + w], wt);
}

// ---------- W-pass bilinear ----------

__global__ __launch_bounds__(256) void k_ci(const float* __restrict__ th,
                                            float* __restrict__ ci) {
#pragma clang fp contract(off)
  int e = blockIdx.x * 256 + threadIdx.x;
  if (e >= 16 * 132 * 132) return;
  int wp = e % 132;
  int rest = e / 132;
  int hp = rest % 132;
  int bd = rest / 132;
  const float R = (float)(65.0 / 131.0);
  float pos = (float)wp * R;
  int j0 = (int)floorf(pos);
  if (j0 < 0) j0 = 0;
  if (j0 > 65) j0 = 65;
  int j1 = j0 + 1;
  if (j1 > 65) j1 = 65;
  float wu = pos - (float)j0;
  const float* t = th + (size_t)bd * 132 * 66;
  ci[((size_t)bd * 132 + hp) * 132 + wp] =
      bilerp1(t[hp * 66 + j0], t[hp * 66 + j1], wu);
}

// ---------- argmin selections ----------

__global__ __launch_bounds__(128) void k_sel0(const float* __restrict__ ci,
                                              int* __restrict__ ind0t,
                                              float* __restrict__ c1sel) {
#pragma clang fp contract(off)
  __shared__ float col0[132], col1[132];
  int bw = blockIdx.x;
  int b = bw / 132, w = bw % 132;
  int tid = threadIdx.x;
  for (int h = tid; h < 132; h += 128) {
    col0[h] = ci[((size_t)(b * 2) * 132 + h) * 132 + w];
    col1[h] = ci[((size_t)(b * 2 + 1) * 132 + h) * 132 + w];
  }
  __syncthreads();
  if (tid < 64) {
    float gv = grid_val(tid);
    float best = fabsf(col0[0] - gv);
    int bi = 0;
    for (int h = 1; h < 132; ++h) {
      float d2 = fabsf(col0[h] - gv);
      if (d2 < best) { best = d2; bi = h; }
    }
    ind0t[((size_t)b * 64 + tid) * 132 + w] = bi;
    c1sel[((size_t)b * 64 + tid) * 132 + w] = col1[bi];
  }
}

__global__ __launch_bounds__(64) void k_sel1b(const float* __restrict__ c1sel,
                                              int* __restrict__ ind) {
#pragma clang fp contract(off)
  __shared__ float rv[132];
  int b = blockIdx.x >> 6, g0 = blockIdx.x & 63;
  int tid = threadIdx.x;
  for (int w = tid; w < 132; w += 64) rv[w] = c1sel[((size_t)b * 64 + g0) * 132 + w];
  __syncthreads();
  float gv = grid_val(tid);
  float best = fabsf(rv[0] - gv);
  int bi = 0;
  for (int w = 1; w < 132; ++w) {
    float d2 = fabsf(rv[w] - gv);
    if (d2 < best) { best = d2; bi = w; }
  }
  ind[((size_t)b * 64 + g0) * 64 + tid] = bi;
}

// ---------- gather x into cell-contiguous DB[b*4096+cell][256] ----------

__global__ __launch_bounds__(256) void k_db(const float* __restrict__ x,
                                            const int* __restrict__ idxT,
                                            float* __restrict__ db) {
  int t = blockIdx.x * 256 + threadIdx.x;
  int mi = t & 31;
  int cellLocal = (t >> 5) & 4095;
  int b = t >> 17;
  int g = idxT[(size_t)b * NPTS + cellLocal * 32 + mi];
  const float* src = x + ((size_t)b * NPTS + g) * 8;
  float4 lo = *(const float4*)(src);
  float4 hi = *(const float4*)(src + 4);
  float* dst = db + (size_t)t * 8;
  *(float4*)(dst) = lo;
  *(float4*)(dst + 4) = hi;
}

// ---------- final bicubic: lanes=channels, LDS transpose ----------

__global__ __launch_bounds__(256) void k_final3(const float* __restrict__ db,
                                                const int* __restrict__ ind,
                                                const int* __restrict__ ind0t,
                                                float* __restrict__ outp) {
#pragma clang fp contract(off)
  __shared__ int sRI[256], sCI[256];
  __shared__ float sWH[256], sWW[256];
  __shared__ float tile[64][65];

  const int bid = blockIdx.x;
  const int b = bid >> 8;
  const int p = (bid >> 2) & 63;
  const int cg = bid & 3;
  const int tid = threadIdx.x;
  const float R = (float)(65.0 / 131.0);

  if (tid < 64) {
    int qt = tid;
    int wstar = ind[((size_t)b * 64 + qt) * 64 + p];
    int hstar = ind0t[((size_t)b * 64 + qt) * 132 + wstar];
    float posh = (float)hstar * R;
    int i0h = (int)floorf(posh);
    float frh = posh - (float)i0h;
    float posw = (float)wstar * R;
    int i0w = (int)floorf(posw);
    float frw = posw - (float)i0w;
#pragma unroll
    for (int k = 0; k < 4; ++k) {
      int I = i0h + k - 1;
      I = I < 0 ? 0 : (I > 65 ? 65 : I);
      int rI = I - 1;
      sRI[qt * 4 + k] = rI < 0 ? 0 : (rI > 63 ? 63 : rI);
      sWH[qt * 4 + k] = cubw(frh - (float)(k - 1));
      int J = i0w + k - 1;
      J = J < 0 ? 0 : (J > 65 ? 65 : J);
      int cJ = J - 1;
      sCI[qt * 4 + k] = cJ < 0 ? 0 : (cJ > 63 ? 63 : cJ);
      sWW[qt * 4 + k] = cubw(frw - (float)(k - 1));
    }
  }
  __syncthreads();

  const int wave = tid >> 6, lane = tid & 63;
  const int ch = cg * 64 + lane;
  const size_t dbb = (size_t)(b * 4096) * 256 + ch;

  for (int s = 0; s < 16; ++s) {
    int qt = wave * 16 + s;
    float a = 0.0f;
#pragma unroll
    for (int l = 0; l < 4; ++l) {
      float t = 0.0f;
#pragma unroll
      for (int k = 0; k < 4; ++k) {
        float v = db[dbb + (size_t)(sRI[qt * 4 + k] * 64 + sCI[qt * 4 + l]) * 256];
        t = fmaf(v, sWH[qt * 4 + k], t);
      }
      a = fmaf(t, sWW[qt * 4 + l], a);
    }
    tile[qt][lane] = a;
  }
  __syncthreads();

  for (int it = 0; it < 16; ++it) {
    int qt2 = tid & 63;
    int cc = (tid >> 6) * 16 + it;
    outp[(((size_t)b * 256 + cg * 64 + cc) * 64 + p) * 64 + qt2] = tile[qt2][cc];
  }
}

// ---------- launch ----------

extern "C" void kernel_launch(void* const* d_in, const int* in_sizes, int n_in,
                              void* d_out, int out_size, void* d_ws, size_t ws_size,
                              hipStream_t stream) {
  (void)n_in; (void)out_size; (void)ws_size;
  const float* x;
  const float* coords;
  if (in_sizes[0] == 8388608) {
    x = (const float*)d_in[0];
    coords = (const float*)d_in[1];
  } else {
    coords = (const float*)d_in[0];
    x = (const float*)d_in[1];
  }
  float* outp = (float*)d_out;
  char* ws = (char*)d_ws;

  uint32_t* KA = (uint32_t*)(ws + 0);
  uint32_t* KB = (uint32_t*)(ws + 4194304);
  uint32_t* HIST = (uint32_t*)(ws + 8388608);
  int* IDX1 = (int*)(ws + 8650752);
  float* CP = (float*)(ws + 0);
  float* TH = (float*)(ws + 279040);
  float* CI = (float*)(ws + 836864);
  float* DB = (float*)(ws + 0);

  size_t P = 33554432;
  int* IDXT = (int*)(ws + P);          P += 4194304;
  float* CM = (float*)(ws + P);        P += 262144;
  int* IND0T = (int*)(ws + P);         P += 270336;
  float* C1SEL = (float*)(ws + P);     P += 270336;
  int* IND = (int*)(ws + P);           P += 131072;
  float* QB1 = (float*)(ws + P);       P += 2048;

  k_keys1<<<4096, 256, 0, stream>>>(coords, KA);

  k_radix_hist<<<256, 256, 0, stream>>>(KA, HIST, 0);
  k_scan<<<8, 256, 0, stream>>>(HIST, 8192);
  k_radix_scatter<<<256, 256, 0, stream>>>(KA, KB, HIST, 0);
  k_radix_hist<<<256, 256, 0, stream>>>(KB, HIST, 8);
  k_scan<<<8, 256, 0, stream>>>(HIST, 8192);
  k_radix_scatter<<<256, 256, 0, stream>>>(KB, KA, HIST, 8);
  k_radix_hist<<<256, 256, 0, stream>>>(KA, HIST, 16);
  k_scan<<<8, 256, 0, stream>>>(HIST, 8192);
  k_radix_scatter<<<256, 256, 0, stream>>>(KA, KB, HIST, 16);
  k_radix_hist<<<256, 256, 0, stream>>>(KB, HIST, 24);
  k_scan<<<8, 256, 0, stream>>>(HIST, 8192);
  k_radix_scatter<<<256, 256, 0, stream>>>(KB, KA, HIST, 24);

  k_quantile1<<<8, 64, 0, stream>>>(KA, QB1);

  k_bhist<<<256, 256, 0, stream>>>(coords, QB1, HIST);
  k_scan<<<8, 256, 0, stream>>>(HIST, 2048);
  k_bscatter<<<256, 256, 0, stream>>>(coords, QB1, HIST, IDX1);

  k_level2<<<512, 256, 0, stream>>>(IDX1, coords, IDXT, CM);

  k_cp2<<<8, 256, 0, stream>>>(CM, CP);
  k_th<<<545, 256, 0, stream>>>(CP, TH);
  k_ci<<<1089, 256, 0, stream>>>(TH, CI);
  k_sel0<<<1056, 128, 0, stream>>>(CI, IND0T, C1SEL);
  k_sel1b<<<512, 64, 0, stream>>>(C1SEL, IND);

  k_db<<<4096, 256, 0, stream>>>(x, IDXT, DB);
  k_final3<<<2048, 256, 0, stream>>>(DB, IND, IND0T, outp);
}

// Round 15
// 288.374 us; speedup vs baseline: 4.7669x; 1.0408x over previous
//
#include <hip/hip_runtime.h>
#include <stdint.h>

#define NPTS 131072

// ---------- helpers (XLA:GPU contraction semantics: fma-fused) ----------

__device__ __forceinline__ float cubw(float t) {
#pragma clang fp contract(off)
  float at = fabsf(t);
  if (at <= 1.0f) {
    float u = fmaf(1.25f, at, -2.25f);
    u = u * at;
    return fmaf(u, at, 1.0f);
  } else if (at < 2.0f) {
    float u = at - 5.0f;
    u = fmaf(u, at, 8.0f);
    u = fmaf(u, at, -4.0f);
    return u * -0.75f;
  }
  return 0.0f;
}

__device__ __forceinline__ float quant_frac(int t) {
#pragma clang fp contract(off)
  return (float)(t + 1) * 0.015625f;
}

__device__ __forceinline__ float grid_val(int i) {
#pragma clang fp contract(off)
  return (float)i * (1.0f / 63.0f);
}

__device__ __forceinline__ float jax_quantile_lerp(float vlo, float vhi, float q) {
#pragma clang fp contract(off)
  float lowf = floorf(q);
  float highf = ceilf(q);
  float hw = q - lowf;
  float lw = highf - q;
  float bh = vhi * hw;
  return fmaf(vlo, lw, bh);
}

__device__ __forceinline__ float bilerp1(float a, float b, float w) {
#pragma clang fp contract(off)
  float omw = 1.0f - w;
  float bw = b * w;
  return fmaf(a, omw, bw);
}

template <int NB>
__device__ __forceinline__ unsigned long long match_mask(uint32_t d) {
  unsigned long long m = ~0ull;
#pragma unroll
  for (int i = 0; i < NB; ++i) {
    unsigned long long bal = __ballot((int)((d >> i) & 1u));
    m &= ((d >> i) & 1u) ? bal : ~bal;
  }
  return m;
}

// adjusted level-1 key: u(fl(x + 8b)) - u(8b)   (order-preserving, <= 2^20 for b>=1)
__device__ __forceinline__ uint32_t l1key(const float* coords, int batch, int idx) {
#pragma clang fp contract(off)
  float off = (float)(8 * batch);
  float c = coords[(size_t)(batch * 2) * NPTS + idx] + off;
  return __float_as_uint(c) - __float_as_uint(off);
}

// ---------- LSD radix: generic hist/scan/scatter on materialized keys ----------

__global__ __launch_bounds__(256) void k_radix_hist(const uint32_t* __restrict__ in,
                                                    uint32_t* __restrict__ hist, int shift,
                                                    int batch0) {
  __shared__ uint32_t h[256];
  int tid = threadIdx.x;
  int batch = (blockIdx.x >> 5) + batch0, blk = blockIdx.x & 31;
  h[tid] = 0;
  __syncthreads();
  const uint32_t* keys = in + (size_t)batch * NPTS + (size_t)blk * 4096;
  for (int r = 0; r < 16; ++r) {
    uint32_t d = (keys[r * 256 + tid] >> shift) & 255u;
    atomicAdd(&h[d], 1u);
  }
  __syncthreads();
  hist[((size_t)batch * 256 + tid) * 32 + blk] = h[tid];
}

__global__ __launch_bounds__(256) void k_scan(uint32_t* __restrict__ buf, int len) {
  __shared__ uint32_t tot[256];
  int batch = blockIdx.x, tid = threadIdx.x;
  int per = len >> 8;
  uint32_t* p = buf + (size_t)batch * len + (size_t)tid * per;
  uint32_t s = 0;
  for (int i = 0; i < per; ++i) s += p[i];
  tot[tid] = s;
  __syncthreads();
  if (tid == 0) {
    uint32_t run = 0;
    for (int i = 0; i < 256; ++i) { uint32_t t = tot[i]; tot[i] = run; run += t; }
  }
  __syncthreads();
  uint32_t run = tot[tid];
  for (int i = 0; i < per; ++i) { uint32_t t = p[i]; p[i] = run; run += t; }
}

__global__ __launch_bounds__(256) void k_radix_scatter(const uint32_t* __restrict__ in,
                                                       uint32_t* __restrict__ out,
                                                       const uint32_t* __restrict__ base,
                                                       int shift, int batch0) {
  __shared__ uint32_t whist[4 * 256];
  int tid = threadIdx.x;
  int wv = tid >> 6, lane = tid & 63;
  int batch = (blockIdx.x >> 5) + batch0, blk = blockIdx.x & 31;
  size_t batchbase = (size_t)batch * NPTS;
  const uint32_t* src = in + batchbase + (size_t)blk * 4096 + (size_t)wv * 1024;

  for (int i = tid; i < 4 * 256; i += 256) whist[i] = 0;
  __syncthreads();

  uint32_t keyv[16], posv[16];
#pragma unroll
  for (int r = 0; r < 16; ++r) {
    uint32_t key = src[r * 64 + lane];
    uint32_t d = (key >> shift) & 255u;
    unsigned long long m = match_mask<8>(d);
    unsigned long long below = m & ((1ull << lane) - 1ull);
    uint32_t rank = (uint32_t)__popcll(below);
    uint32_t cnt = (uint32_t)__popcll(m);
    uint32_t bse = whist[wv * 256 + d];
    if (below == 0ull) whist[wv * 256 + d] = bse + cnt;
    keyv[r] = key;
    posv[r] = bse + rank;
  }
  __syncthreads();
  {
    uint32_t a0 = whist[tid], a1 = whist[256 + tid], a2 = whist[512 + tid];
    whist[tid] = 0;
    whist[256 + tid] = a0;
    whist[512 + tid] = a0 + a1;
    whist[768 + tid] = a0 + a1 + a2;
  }
  __syncthreads();
  const uint32_t* bb = base + (size_t)batch * 8192;
#pragma unroll
  for (int r = 0; r < 16; ++r) {
    uint32_t key = keyv[r];
    uint32_t d = (key >> shift) & 255u;
    uint32_t pos = bb[d * 32 + blk] + whist[wv * 256 + d] + posv[r];
    out[batchbase + pos] = key;
  }
}

// pass-0 variants: compute adjusted key from coords inline (no KA materialization)

__global__ __launch_bounds__(256) void k_radix_hist0(const float* __restrict__ coords,
                                                     uint32_t* __restrict__ hist) {
  __shared__ uint32_t h[256];
  int tid = threadIdx.x;
  int batch = blockIdx.x >> 5, blk = blockIdx.x & 31;
  h[tid] = 0;
  __syncthreads();
  for (int r = 0; r < 16; ++r) {
    uint32_t d = l1key(coords, batch, blk * 4096 + r * 256 + tid) & 255u;
    atomicAdd(&h[d], 1u);
  }
  __syncthreads();
  hist[((size_t)batch * 256 + tid) * 32 + blk] = h[tid];
}

__global__ __launch_bounds__(256) void k_radix_scatter0(const float* __restrict__ coords,
                                                        uint32_t* __restrict__ out,
                                                        const uint32_t* __restrict__ base) {
  __shared__ uint32_t whist[4 * 256];
  int tid = threadIdx.x;
  int wv = tid >> 6, lane = tid & 63;
  int batch = blockIdx.x >> 5, blk = blockIdx.x & 31;
  size_t batchbase = (size_t)batch * NPTS;

  for (int i = tid; i < 4 * 256; i += 256) whist[i] = 0;
  __syncthreads();

  uint32_t keyv[16], posv[16];
#pragma unroll
  for (int r = 0; r < 16; ++r) {
    uint32_t key = l1key(coords, batch, blk * 4096 + wv * 1024 + r * 64 + lane);
    uint32_t d = key & 255u;
    unsigned long long m = match_mask<8>(d);
    unsigned long long below = m & ((1ull << lane) - 1ull);
    uint32_t rank = (uint32_t)__popcll(below);
    uint32_t cnt = (uint32_t)__popcll(m);
    uint32_t bse = whist[wv * 256 + d];
    if (below == 0ull) whist[wv * 256 + d] = bse + cnt;
    keyv[r] = key;
    posv[r] = bse + rank;
  }
  __syncthreads();
  {
    uint32_t a0 = whist[tid], a1 = whist[256 + tid], a2 = whist[512 + tid];
    whist[tid] = 0;
    whist[256 + tid] = a0;
    whist[512 + tid] = a0 + a1;
    whist[768 + tid] = a0 + a1 + a2;
  }
  __syncthreads();
  const uint32_t* bb = base + (size_t)batch * 8192;
#pragma unroll
  for (int r = 0; r < 16; ++r) {
    uint32_t key = keyv[r];
    uint32_t d = key & 255u;
    uint32_t pos = bb[d * 32 + blk] + whist[wv * 256 + d] + posv[r];
    out[batchbase + pos] = key;
  }
}

// ---------- level-1 quantiles (batch 0 sorted in A; batches>=1 sorted in B) ----------

__global__ __launch_bounds__(64) void k_quantile1(const uint32_t* __restrict__ sA,
                                                  const uint32_t* __restrict__ sB,
                                                  float* __restrict__ qb1) {
#pragma clang fp contract(off)
  int batch = blockIdx.x, t = threadIdx.x;
  if (t >= 63) return;
  float qv = quant_frac(t);
  float q = qv * 131071.0f;
  int lo = (int)floorf(q);
  const uint32_t* s = (batch == 0 ? sA : sB) + (size_t)batch * NPTS;
  uint32_t u0 = __float_as_uint((float)(8 * batch));
  float vlo = __uint_as_float(s[lo] + u0);
  float vhi = __uint_as_float(s[lo + 1] + u0);
  qb1[batch * 64 + t] = jax_quantile_lerp(vlo, vhi, q);
}

// ---------- level-1 stable counting sort by bucket ----------

__global__ __launch_bounds__(256) void k_bhist(const float* __restrict__ coords,
                                               const float* __restrict__ qb1,
                                               uint32_t* __restrict__ hist) {
#pragma clang fp contract(off)
  __shared__ uint32_t h[64];
  __shared__ float qb[63];
  int tid = threadIdx.x;
  int batch = blockIdx.x >> 5, blk = blockIdx.x & 31;
  if (tid < 64) h[tid] = 0;
  if (tid >= 64 && tid < 127) qb[tid - 64] = qb1[batch * 64 + (tid - 64)];
  __syncthreads();
  const float* c = coords + (size_t)(batch * 2) * NPTS + (size_t)blk * 4096;
  float off = (float)(8 * batch);
  for (int r = 0; r < 16; ++r) {
    float v = c[r * 256 + tid] + off;
    uint32_t d = 0;
#pragma unroll
    for (int k = 0; k < 63; ++k) d += (qb[k] <= v) ? 1u : 0u;
    atomicAdd(&h[d], 1u);
  }
  __syncthreads();
  if (tid < 64) hist[((size_t)batch * 64 + tid) * 32 + blk] = h[tid];
}

__global__ __launch_bounds__(256) void k_bscatter(const float* __restrict__ coords,
                                                  const float* __restrict__ qb1,
                                                  const uint32_t* __restrict__ base,
                                                  int* __restrict__ idxout) {
#pragma clang fp contract(off)
  __shared__ uint32_t whist[4 * 64];
  __shared__ float qb[63];
  int tid = threadIdx.x;
  int wv = tid >> 6, lane = tid & 63;
  int batch = blockIdx.x >> 5, blk = blockIdx.x & 31;
  if (tid < 4 * 64) whist[tid] = 0;
  if (tid >= 192 && tid < 255) qb[tid - 192] = qb1[batch * 64 + (tid - 192)];
  __syncthreads();
  const float* c = coords + (size_t)(batch * 2) * NPTS + (size_t)blk * 4096 + (size_t)wv * 1024;
  float off = (float)(8 * batch);
  uint32_t bkv[16], rkv[16];
#pragma unroll
  for (int r = 0; r < 16; ++r) {
    float v = c[r * 64 + lane] + off;
    uint32_t d = 0;
#pragma unroll
    for (int k = 0; k < 63; ++k) d += (qb[k] <= v) ? 1u : 0u;
    unsigned long long m = match_mask<6>(d);
    unsigned long long below = m & ((1ull << lane) - 1ull);
    uint32_t rank = (uint32_t)__popcll(below);
    uint32_t cnt = (uint32_t)__popcll(m);
    uint32_t bse = whist[wv * 64 + d];
    if (below == 0ull) whist[wv * 64 + d] = bse + cnt;
    bkv[r] = d;
    rkv[r] = bse + rank;
  }
  __syncthreads();
  if (tid < 64) {
    uint32_t a0 = whist[tid], a1 = whist[64 + tid], a2 = whist[128 + tid];
    whist[tid] = 0;
    whist[64 + tid] = a0;
    whist[128 + tid] = a0 + a1;
    whist[192 + tid] = a0 + a1 + a2;
  }
  __syncthreads();
  const uint32_t* bb = base + (size_t)batch * 2048;
  int ibase = blk * 4096 + wv * 1024;
#pragma unroll
  for (int r = 0; r < 16; ++r) {
    uint32_t d = bkv[r];
    uint32_t pos = bb[d * 32 + blk] + whist[wv * 64 + d] + rkv[r];
    idxout[(size_t)batch * NPTS + pos] = ibase + r * 64 + lane;
  }
}

// ---------- level-2: adjusted-key radix (2 passes for rows>=1) + bucket sort ----------

__global__ __launch_bounds__(256) void k_level2(const int* __restrict__ idx1,
                                                const float* __restrict__ coords,
                                                int* __restrict__ idxT,
                                                float* __restrict__ cm) {
#pragma clang fp contract(off)
  __shared__ int gidx[2048];
  __shared__ float ckey[2048];
  __shared__ uint32_t sbA[2048];
  __shared__ uint32_t sbB[2048];
  __shared__ uint32_t whist[4 * 256];
  __shared__ uint32_t base[256];
  __shared__ uint32_t wavetot[4];
  __shared__ float qb[63];

  const int tid = threadIdx.x;
  const int wv = tid >> 6, lane = tid & 63;
  const int row = blockIdx.x;
  const int b = row >> 6, i1 = row & 63;
  const float offf = (float)(512 * row);
  const uint32_t u0 = __float_as_uint(offf);

  for (int j = tid; j < 2048; j += 256) {
    int g = idx1[(size_t)b * NPTS + i1 * 2048 + j];
    gidx[j] = g;
    float cv = coords[((size_t)(b * 2 + 1)) * NPTS + g] + offf;
    ckey[j] = cv;
    sbA[j] = __float_as_uint(cv) - u0;  // adjusted: <= 2^14 for row>=1
  }
  __syncthreads();

  const int npass = (row == 0) ? 4 : 2;
  uint32_t* A = sbA;
  uint32_t* B = sbB;
  for (int pass = 0; pass < npass; ++pass) {
    const int shift = pass * 8;
    for (int i = tid; i < 1024; i += 256) whist[i] = 0;
    __syncthreads();
    uint32_t keyv[8], posv[8];
#pragma unroll
    for (int r = 0; r < 8; ++r) {
      int j = wv * 512 + r * 64 + lane;
      uint32_t key = A[j];
      uint32_t d = (key >> shift) & 255u;
      unsigned long long m = match_mask<8>(d);
      unsigned long long below = m & ((1ull << lane) - 1ull);
      uint32_t rank = (uint32_t)__popcll(below);
      uint32_t cnt = (uint32_t)__popcll(m);
      uint32_t bse = whist[wv * 256 + d];
      if (below == 0ull) whist[wv * 256 + d] = bse + cnt;
      keyv[r] = key;
      posv[r] = bse + rank;
    }
    __syncthreads();
    {
      uint32_t a0 = whist[tid], a1 = whist[256 + tid], a2 = whist[512 + tid],
               a3 = whist[768 + tid];
      base[tid] = a0 + a1 + a2 + a3;
      whist[tid] = 0;
      whist[256 + tid] = a0;
      whist[512 + tid] = a0 + a1;
      whist[768 + tid] = a0 + a1 + a2;
    }
    __syncthreads();
    {
      uint32_t v = base[tid];
      uint32_t inc = v;
#pragma unroll
      for (int d2 = 1; d2 < 64; d2 <<= 1) {
        uint32_t u = __shfl_up(inc, d2, 64);
        if (lane >= d2) inc += u;
      }
      if (lane == 63) wavetot[wv] = inc;
      __syncthreads();
      uint32_t woff = 0;
      for (int w2 = 0; w2 < wv; ++w2) woff += wavetot[w2];
      base[tid] = inc - v + woff;
    }
    __syncthreads();
#pragma unroll
    for (int r = 0; r < 8; ++r) {
      uint32_t d = (keyv[r] >> shift) & 255u;
      B[base[d] + whist[wv * 256 + d] + posv[r]] = keyv[r];
    }
    __syncthreads();
    uint32_t* t = A;
    A = B;
    B = t;
  }
  // npass even -> sorted adjusted keys in sbA

  if (tid < 63) {
    float qv = quant_frac(tid);
    float q = qv * 2047.0f;
    int lo = (int)floorf(q);
    float vlo = __uint_as_float(sbA[lo] + u0);
    float vhi = __uint_as_float(sbA[lo + 1] + u0);
    qb[tid] = jax_quantile_lerp(vlo, vhi, q);
  }
  for (int i = tid; i < 256; i += 256) whist[i] = 0;
  __syncthreads();

  uint32_t dv[8], pv[8];
#pragma unroll
  for (int r = 0; r < 8; ++r) {
    int j = wv * 512 + r * 64 + lane;
    float cv = ckey[j];
    uint32_t d = 0;
#pragma unroll
    for (int k = 0; k < 63; ++k) d += (qb[k] <= cv) ? 1u : 0u;
    unsigned long long m = match_mask<6>(d);
    unsigned long long below = m & ((1ull << lane) - 1ull);
    uint32_t rank = (uint32_t)__popcll(below);
    uint32_t cnt = (uint32_t)__popcll(m);
    uint32_t bse = whist[wv * 64 + d];
    if (below == 0ull) whist[wv * 64 + d] = bse + cnt;
    dv[r] = d;
    pv[r] = bse + rank;
  }
  __syncthreads();
  if (tid < 64) {
    uint32_t a0 = whist[tid], a1 = whist[64 + tid], a2 = whist[128 + tid],
             a3 = whist[192 + tid];
    base[tid] = a0 + a1 + a2 + a3;
    whist[tid] = 0;
    whist[64 + tid] = a0;
    whist[128 + tid] = a0 + a1;
    whist[192 + tid] = a0 + a1 + a2;
  }
  __syncthreads();
  if (wv == 0) {
    uint32_t v = base[lane];
    uint32_t inc = v;
#pragma unroll
    for (int d2 = 1; d2 < 64; d2 <<= 1) {
      uint32_t u = __shfl_up(inc, d2, 64);
      if (lane >= d2) inc += u;
    }
    base[lane] = inc - v;
  }
  __syncthreads();
#pragma unroll
  for (int r = 0; r < 8; ++r) {
    int j = wv * 512 + r * 64 + lane;
    uint32_t pos = base[dv[r]] + whist[wv * 64 + dv[r]] + pv[r];
    sbB[pos] = (uint32_t)j;
  }
  __syncthreads();

  for (int p = tid; p < 2048; p += 256)
    idxT[(size_t)b * NPTS + i1 * 2048 + p] = gidx[sbB[p]];

  if (tid < 128) {
    int i2 = tid >> 1, d = tid & 1;
    float v[32];
#pragma unroll
    for (int m2 = 0; m2 < 32; ++m2)
      v[m2] = coords[((size_t)(b * 2 + d)) * NPTS + gidx[sbB[i2 * 32 + m2]]];
#pragma unroll
    for (int r = 0; r < 32; ++r) {
#pragma unroll
      for (int i = (r & 1); i + 1 < 32; i += 2) {
        float a = v[i], c2 = v[i + 1];
        v[i] = fminf(a, c2);
        v[i + 1] = fmaxf(a, c2);
      }
    }
    cm[(((size_t)(b * 2 + d)) * 64 + i1) * 64 + i2] = v[15];
  }
}

// ---------- padded coord grid CP[b*2+d][66][66] ----------

__global__ __launch_bounds__(256) void k_cp2(const float* __restrict__ cm,
                                             float* __restrict__ cp) {
#pragma clang fp contract(off)
  __shared__ float cp0[66][66];
  __shared__ float cp1[66][66];
  const int b = blockIdx.x;
  const int tid = threadIdx.x;
  const float* m0 = cm + (size_t)(b * 2) * 4096;
  const float* m1 = cm + (size_t)(b * 2 + 1) * 4096;

  for (int i = tid; i < 4096; i += 256) {
    int i1 = i >> 6, i2 = i & 63;
    cp0[1 + i1][1 + i2] = m0[i];
    cp1[1 + i1][1 + i2] = m1[i];
  }
  __syncthreads();

  if (tid < 64) {
    int i2 = tid;
    float mn = m0[i2], mx = m0[i2];
    for (int i1 = 1; i1 < 64; ++i1) {
      float v = m0[i1 * 64 + i2];
      mn = fminf(mn, v);
      mx = fmaxf(mx, v);
    }
    cp0[0][1 + i2] = mn - 0.5f;
    cp0[65][1 + i2] = mx + 0.5f;
  } else if (tid < 128) {
    int i1 = tid - 64;
    float mn = m1[i1 * 64], mx = m1[i1 * 64];
    for (int i2 = 1; i2 < 64; ++i2) {
      float v = m1[i1 * 64 + i2];
      mn = fminf(mn, v);
      mx = fmaxf(mx, v);
    }
    cp1[1 + i1][0] = mn - 0.5f;
    cp1[1 + i1][65] = mx + 0.5f;
  }
  __syncthreads();

  if (tid < 66) {
    cp0[tid][0] = cp0[tid][1];
    cp0[tid][65] = cp0[tid][64];
  } else if (tid < 132) {
    int w = tid - 66;
    cp1[0][w] = cp1[1][w];
    cp1[65][w] = cp1[64][w];
  }
  __syncthreads();

  for (int e = tid; e < 4356; e += 256) {
    int h = e / 66, w = e % 66;
    cp[((size_t)(b * 2) * 66 + h) * 66 + w] = cp0[h][w];
    cp[((size_t)(b * 2 + 1) * 66 + h) * 66 + w] = cp1[h][w];
  }
}

// ---------- fused bilinear (H pass value rounded, then W pass -- bit-identical) ----------

__global__ __launch_bounds__(256) void k_thci(const float* __restrict__ cp,
                                              float* __restrict__ ci) {
#pragma clang fp contract(off)
  int e = blockIdx.x * 256 + threadIdx.x;
  if (e >= 16 * 132 * 132) return;
  int wp = e % 132;
  int rest = e / 132;
  int hp = rest % 132;
  int bd = rest / 132;
  const float R = (float)(65.0 / 131.0);

  float posh = (float)hp * R;
  int r0 = (int)floorf(posh);
  if (r0 < 0) r0 = 0;
  if (r0 > 65) r0 = 65;
  int r1 = r0 + 1;
  if (r1 > 65) r1 = 65;
  float wt = posh - (float)r0;

  float posw = (float)wp * R;
  int j0 = (int)floorf(posw);
  if (j0 < 0) j0 = 0;
  if (j0 > 65) j0 = 65;
  int j1 = j0 + 1;
  if (j1 > 65) j1 = 65;
  float wu = posw - (float)j0;

  const float* p = cp + (size_t)bd * 66 * 66;
  float ta = bilerp1(p[r0 * 66 + j0], p[r1 * 66 + j0], wt);
  float tb = bilerp1(p[r0 * 66 + j1], p[r1 * 66 + j1], wt);
  ci[((size_t)bd * 132 + hp) * 132 + wp] = bilerp1(ta, tb, wu);
}

// ---------- argmin selections ----------

__global__ __launch_bounds__(128) void k_sel0(const float* __restrict__ ci,
                                              int* __restrict__ ind0t,
                                              float* __restrict__ c1sel) {
#pragma clang fp contract(off)
  __shared__ float col0[132], col1[132];
  int bw = blockIdx.x;
  int b = bw / 132, w = bw % 132;
  int tid = threadIdx.x;
  for (int h = tid; h < 132; h += 128) {
    col0[h] = ci[((size_t)(b * 2) * 132 + h) * 132 + w];
    col1[h] = ci[((size_t)(b * 2 + 1) * 132 + h) * 132 + w];
  }
  __syncthreads();
  if (tid < 64) {
    float gv = grid_val(tid);
    float best = fabsf(col0[0] - gv);
    int bi = 0;
    for (int h = 1; h < 132; ++h) {
      float d2 = fabsf(col0[h] - gv);
      if (d2 < best) { best = d2; bi = h; }
    }
    ind0t[((size_t)b * 64 + tid) * 132 + w] = bi;
    c1sel[((size_t)b * 64 + tid) * 132 + w] = col1[bi];
  }
}

__global__ __launch_bounds__(64) void k_sel1b(const float* __restrict__ c1sel,
                                              int* __restrict__ ind) {
#pragma clang fp contract(off)
  __shared__ float rv[132];
  int b = blockIdx.x >> 6, g0 = blockIdx.x & 63;
  int tid = threadIdx.x;
  for (int w = tid; w < 132; w += 64) rv[w] = c1sel[((size_t)b * 64 + g0) * 132 + w];
  __syncthreads();
  float gv = grid_val(tid);
  float best = fabsf(rv[0] - gv);
  int bi = 0;
  for (int w = 1; w < 132; ++w) {
    float d2 = fabsf(rv[w] - gv);
    if (d2 < best) { best = d2; bi = w; }
  }
  ind[((size_t)b * 64 + g0) * 64 + tid] = bi;
}

// ---------- gather x into cell-contiguous DB[b*4096+cell][256] ----------

__global__ __launch_bounds__(256) void k_db(const float* __restrict__ x,
                                            const int* __restrict__ idxT,
                                            float* __restrict__ db) {
  int t = blockIdx.x * 256 + threadIdx.x;
  int mi = t & 31;
  int cellLocal = (t >> 5) & 4095;
  int b = t >> 17;
  int g = idxT[(size_t)b * NPTS + cellLocal * 32 + mi];
  const float* src = x + ((size_t)b * NPTS + g) * 8;
  float4 lo = *(const float4*)(src);
  float4 hi = *(const float4*)(src + 4);
  float* dst = db + (size_t)t * 8;
  *(float4*)(dst) = lo;
  *(float4*)(dst + 4) = hi;
}

// ---------- final bicubic: lanes=channels, LDS transpose ----------

__global__ __launch_bounds__(256) void k_final3(const float* __restrict__ db,
                                                const int* __restrict__ ind,
                                                const int* __restrict__ ind0t,
                                                float* __restrict__ outp) {
#pragma clang fp contract(off)
  __shared__ int sRI[256], sCI[256];
  __shared__ float sWH[256], sWW[256];
  __shared__ float tile[64][65];

  const int bid = blockIdx.x;
  const int b = bid >> 8;
  const int p = (bid >> 2) & 63;
  const int cg = bid & 3;
  const int tid = threadIdx.x;
  const float R = (float)(65.0 / 131.0);

  if (tid < 64) {
    int qt = tid;
    int wstar = ind[((size_t)b * 64 + qt) * 64 + p];
    int hstar = ind0t[((size_t)b * 64 + qt) * 132 + wstar];
    float posh = (float)hstar * R;
    int i0h = (int)floorf(posh);
    float frh = posh - (float)i0h;
    float posw = (float)wstar * R;
    int i0w = (int)floorf(posw);
    float frw = posw - (float)i0w;
#pragma unroll
    for (int k = 0; k < 4; ++k) {
      int I = i0h + k - 1;
      I = I < 0 ? 0 : (I > 65 ? 65 : I);
      int rI = I - 1;
      sRI[qt * 4 + k] = rI < 0 ? 0 : (rI > 63 ? 63 : rI);
      sWH[qt * 4 + k] = cubw(frh - (float)(k - 1));
      int J = i0w + k - 1;
      J = J < 0 ? 0 : (J > 65 ? 65 : J);
      int cJ = J - 1;
      sCI[qt * 4 + k] = cJ < 0 ? 0 : (cJ > 63 ? 63 : cJ);
      sWW[qt * 4 + k] = cubw(frw - (float)(k - 1));
    }
  }
  __syncthreads();

  const int wave = tid >> 6, lane = tid & 63;
  const int ch = cg * 64 + lane;
  const size_t dbb = (size_t)(b * 4096) * 256 + ch;

  for (int s = 0; s < 16; ++s) {
    int qt = wave * 16 + s;
    float a = 0.0f;
#pragma unroll
    for (int l = 0; l < 4; ++l) {
      float t = 0.0f;
#pragma unroll
      for (int k = 0; k < 4; ++k) {
        float v = db[dbb + (size_t)(sRI[qt * 4 + k] * 64 + sCI[qt * 4 + l]) * 256];
        t = fmaf(v, sWH[qt * 4 + k], t);
      }
      a = fmaf(t, sWW[qt * 4 + l], a);
    }
    tile[qt][lane] = a;
  }
  __syncthreads();

  for (int it = 0; it < 16; ++it) {
    int qt2 = tid & 63;
    int cc = (tid >> 6) * 16 + it;
    outp[(((size_t)b * 256 + cg * 64 + cc) * 64 + p) * 64 + qt2] = tile[qt2][cc];
  }
}

// ---------- launch ----------

extern "C" void kernel_launch(void* const* d_in, const int* in_sizes, int n_in,
                              void* d_out, int out_size, void* d_ws, size_t ws_size,
                              hipStream_t stream) {
  (void)n_in; (void)out_size; (void)ws_size;
  const float* x;
  const float* coords;
  if (in_sizes[0] == 8388608) {
    x = (const float*)d_in[0];
    coords = (const float*)d_in[1];
  } else {
    coords = (const float*)d_in[0];
    x = (const float*)d_in[1];
  }
  float* outp = (float*)d_out;
  char* ws = (char*)d_ws;

  uint32_t* KA = (uint32_t*)(ws + 0);
  uint32_t* KB = (uint32_t*)(ws + 4194304);
  uint32_t* HIST = (uint32_t*)(ws + 8388608);
  int* IDX1 = (int*)(ws + 8650752);
  float* CP = (float*)(ws + 0);
  float* CI = (float*)(ws + 279040);
  float* DB = (float*)(ws + 0);

  size_t P = 33554432;
  int* IDXT = (int*)(ws + P);          P += 4194304;
  float* CM = (float*)(ws + P);        P += 262144;
  int* IND0T = (int*)(ws + P);         P += 270336;
  float* C1SEL = (float*)(ws + P);     P += 270336;
  int* IND = (int*)(ws + P);           P += 131072;
  float* QB1 = (float*)(ws + P);       P += 2048;

  // level-1 radix on adjusted keys: pass0 (fused key calc) -> KA; pass1 KA->KB;
  // pass2 KB->KA; pass3 only batch 0: KA->KB ... careful with parity:
  // P0: coords -> KA (shift 0)
  k_radix_hist0<<<256, 256, 0, stream>>>(coords, HIST);
  k_scan<<<8, 256, 0, stream>>>(HIST, 8192);
  k_radix_scatter0<<<256, 256, 0, stream>>>(coords, KA, HIST);
  // P1: KA -> KB (shift 8)
  k_radix_hist<<<256, 256, 0, stream>>>(KA, HIST, 8, 0);
  k_scan<<<8, 256, 0, stream>>>(HIST, 8192);
  k_radix_scatter<<<256, 256, 0, stream>>>(KA, KB, HIST, 8, 0);
  // P2: KB -> KA (shift 16)
  k_radix_hist<<<256, 256, 0, stream>>>(KB, HIST, 16, 0);
  k_scan<<<8, 256, 0, stream>>>(HIST, 8192);
  k_radix_scatter<<<256, 256, 0, stream>>>(KB, KA, HIST, 16, 0);
  // P3 (batch 0 only; batches>=1 have zero high byte): KA -> KB (shift 24)
  k_radix_hist<<<32, 256, 0, stream>>>(KA, HIST, 24, 0);
  k_scan<<<1, 256, 0, stream>>>(HIST, 8192);
  k_radix_scatter<<<32, 256, 0, stream>>>(KA, KB, HIST, 24, 0);
  // batch 0 sorted in KB; batches>=1 sorted in KA
  k_quantile1<<<8, 64, 0, stream>>>(KB, KA, QB1);

  k_bhist<<<256, 256, 0, stream>>>(coords, QB1, HIST);
  k_scan<<<8, 256, 0, stream>>>(HIST, 2048);
  k_bscatter<<<256, 256, 0, stream>>>(coords, QB1, HIST, IDX1);

  k_level2<<<512, 256, 0, stream>>>(IDX1, coords, IDXT, CM);

  k_cp2<<<8, 256, 0, stream>>>(CM, CP);
  k_thci<<<1089, 256, 0, stream>>>(CP, CI);
  k_sel0<<<1056, 128, 0, stream>>>(CI, IND0T, C1SEL);
  k_sel1b<<<512, 64, 0, stream>>>(C1SEL, IND);

  k_db<<<4096, 256, 0, stream>>>(x, IDXT, DB);
  k_final3<<<2048, 256, 0, stream>>>(DB, IND, IND0T, outp);
}